// Round 12
// baseline (456.302 us; speedup 1.0000x reference)
//
#include <hip/hip_runtime.h>
#include <hip/hip_bf16.h>
#include <math.h>

// GAT block: N=50000, E=800000, H_IN=64, HEADS=4, C=16 (F=64 out)
// Round 12: aggregation fused into buckets. One block per 128-dst bucket
// accumulates w*h into LDS f32 (pad-65 -> 2-way banks = free) via ds_add_f32,
// wave-per-edge with unroll-16 for MLP. scatter2/sorted_src/offs deleted.
// Node MFMA part byte-identical; scans/bucket_write pattern kept (NPB=128,
// EPB=8192 so the blockcnt scan stays 2-level: 391*98=38318 entries).

#define BLK 256
#define NPB 128            // nodes (dsts) per bucket
#define DSH 7              // log2(NPB)
#define NBMAX 392          // LDS counter array size (>= nbBucket=391)
#define EPB 8192           // edges per counting/writing block (32/thread)

typedef __attribute__((ext_vector_type(8))) short short8;
typedef __attribute__((ext_vector_type(4))) float f32x4;

static __device__ __forceinline__ unsigned short f2bf(float f) {
    union { float f; unsigned u; } v; v.f = f;
    return (unsigned short)((v.u + 0x7FFF + ((v.u >> 16) & 1)) >> 16);
}
static __device__ __forceinline__ unsigned short f2fh(float f) {
    union { _Float16 h; unsigned short u; } v; v.h = (_Float16)f; return v.u;
}
static __device__ __forceinline__ float fh2f(unsigned short u) {
    union { _Float16 h; unsigned short u; } v; v.u = u; return (float)v.h;
}

// ---------------- K0: pack weights + fold att vectors ------------------------
__global__ void prep_weights(const float* __restrict__ W,
                             const float* __restrict__ skipW,
                             const float* __restrict__ conv_bias,
                             const float* __restrict__ skip_b,
                             const float* __restrict__ att_src,
                             const float* __restrict__ att_dst,
                             unsigned short* __restrict__ wfrag,
                             float* __restrict__ bias64,
                             float* __restrict__ watt_s,
                             float* __restrict__ watt_d) {
    const int t = threadIdx.x;
    for (int idx = t; idx < 8192; idx += BLK) {
        const int j = idx & 7;
        const int lane = (idx >> 3) & 63;
        const int kh = (idx >> 9) & 1;
        const int ct = idx >> 10;
        const int k = kh * 32 + (lane >> 4) * 8 + j;
        const int c = ct * 16 + (lane & 15);
        const float v = (c < 64) ? W[k * 64 + c] : skipW[k * 64 + (c - 64)];
        wfrag[idx] = f2bf(v);
    }
    if (t < 64) bias64[t] = conv_bias[t] + skip_b[t];
    {   // t in [0,256): hh = t>>6, k = t&63
        const int hh = t >> 6, k = t & 63;
        float ssum = 0.f, dsum = 0.f;
#pragma unroll
        for (int c = 0; c < 16; ++c) {
            const float wv = W[k * 64 + hh * 16 + c];
            ssum = fmaf(wv, att_src[hh * 16 + c], ssum);
            dsum = fmaf(wv, att_dst[hh * 16 + c], dsum);
        }
        watt_s[hh * 64 + k] = ssum;
        watt_d[hh * 64 + k] = dsum;
    }
}

// ---------------- K1: fused node transform (MFMA) | bucket COUNT -------------
__global__ __launch_bounds__(BLK) void node_bcount(
    const float* __restrict__ x, const unsigned short* __restrict__ wfrag,
    const float* __restrict__ bias64, const float* __restrict__ watt_s,
    const float* __restrict__ watt_d,
    unsigned short* __restrict__ h16, float* __restrict__ base,
    float* __restrict__ a_src, float* __restrict__ a_dst, int n,
    const int* __restrict__ ei_raw, int* __restrict__ blockcnt,
    int n_edges, int nbNode, int nbB, int nbBucket) {
    __shared__ unsigned short sfrag[4 * 64 * 16];  // 8KB (node part)
    __shared__ float swatt[512];                   // 2KB (node part)
    __shared__ int s_is64;
    __shared__ int bh[NBMAX];
    const int t = threadIdx.x;

    if (blockIdx.x >= nbNode) {   // ---------------- count part (dst only)
        if (t == 0) {
            int all0 = 1;
            for (int i = 1; i < 128; i += 2) all0 &= (ei_raw[i] == 0);
            s_is64 = all0;
        }
        for (int b = t; b < NBMAX; b += BLK) bh[b] = 0;
        __syncthreads();
        const int blk = blockIdx.x - nbNode;
        const int e0 = blk * EPB;
        const int is64 = s_is64;
        const long long* e64 = (const long long*)ei_raw;
#pragma unroll
        for (int i = 0; i < 32; ++i) {
            const int e = e0 + i * BLK + t;
            if (e < n_edges) {
                const int d = is64 ? (int)e64[n_edges + e] : ei_raw[n_edges + e];
                atomicAdd(&bh[d >> DSH], 1);        // LDS atomic only
            }
        }
        __syncthreads();
        for (int b = t; b < nbBucket; b += BLK)
            blockcnt[(size_t)b * nbB + blk] = bh[b];
        return;
    }

    // ---------------- node transform part (unchanged)
    const int rowBase = blockIdx.x * 64;

    swatt[t] = watt_s[t];
    swatt[256 + t] = watt_d[t];

    const int r = t >> 2;
    const int c0 = (t & 3) << 4;
    const int grow = rowBase + r;
    float vals[16];
    if (grow < n) {
        const float4* xp = reinterpret_cast<const float4*>(x + (size_t)grow * 64 + c0);
        float4 a0 = xp[0], a1 = xp[1], a2 = xp[2], a3 = xp[3];
        vals[0]=a0.x; vals[1]=a0.y; vals[2]=a0.z; vals[3]=a0.w;
        vals[4]=a1.x; vals[5]=a1.y; vals[6]=a1.z; vals[7]=a1.w;
        vals[8]=a2.x; vals[9]=a2.y; vals[10]=a2.z; vals[11]=a2.w;
        vals[12]=a3.x; vals[13]=a3.y; vals[14]=a3.z; vals[15]=a3.w;
    } else {
#pragma unroll
        for (int i = 0; i < 16; ++i) vals[i] = 0.f;
    }

    {
        const int r15 = r & 15, wv = r >> 4;
#pragma unroll
        for (int oo = 0; oo < 2; ++oo) {
            const int oct = (t & 3) * 2 + oo;       // 0..7
            const int kh = oct >> 2, rg = oct & 3;
            const int lane = rg * 16 + r15;
            short8 p;
#pragma unroll
            for (int i = 0; i < 8; ++i) p[i] = (short)f2bf(vals[oo * 8 + i]);
            *reinterpret_cast<short8*>(&sfrag[((wv * 64 + lane) * 2 + kh) * 8]) = p;
        }
    }
    __syncthreads();

    {
#pragma unroll
        for (int hh = 0; hh < 4; ++hh) {
            float s = 0.f, dd = 0.f;
#pragma unroll
            for (int i = 0; i < 16; ++i) {
                s  = fmaf(vals[i], swatt[hh * 64 + c0 + i], s);
                dd = fmaf(vals[i], swatt[256 + hh * 64 + c0 + i], dd);
            }
            s  += __shfl_xor(s, 1);  s  += __shfl_xor(s, 2);
            dd += __shfl_xor(dd, 1); dd += __shfl_xor(dd, 2);
            if ((t & 3) == 0 && grow < n) {
                a_src[grow * 4 + hh] = s;
                a_dst[grow * 4 + hh] = dd;
            }
        }
    }

    const int wave = t >> 6, lane = t & 63;
    const int q = lane & 15, rg = lane >> 4;

    short8 bfr[8][2];
#pragma unroll
    for (int ct = 0; ct < 8; ++ct)
#pragma unroll
        for (int kh = 0; kh < 2; ++kh)
            bfr[ct][kh] = *reinterpret_cast<const short8*>(
                wfrag + (size_t)((ct * 2 + kh) * 64 + lane) * 8);

    short8 afr[2];
#pragma unroll
    for (int kh = 0; kh < 2; ++kh)
        afr[kh] = *reinterpret_cast<const short8*>(
            &sfrag[((wave * 64 + lane) * 2 + kh) * 8]);

    f32x4 acc[8];
#pragma unroll
    for (int i = 0; i < 8; ++i) { acc[i][0]=0.f; acc[i][1]=0.f; acc[i][2]=0.f; acc[i][3]=0.f; }
#pragma unroll
    for (int ct = 0; ct < 8; ++ct)
#pragma unroll
        for (int kh = 0; kh < 2; ++kh)
            acc[ct] = __builtin_amdgcn_mfma_f32_16x16x32_bf16(
                afr[kh], bfr[ct][kh], acc[ct], 0, 0, 0);

    float biasv[4];
#pragma unroll
    for (int i = 0; i < 4; ++i) biasv[i] = bias64[i * 16 + q];

#pragma unroll
    for (int ct = 0; ct < 4; ++ct)
#pragma unroll
        for (int j = 0; j < 4; ++j) {
            const int gr = rowBase + wave * 16 + rg * 4 + j;
            if (gr < n) h16[(size_t)gr * 64 + ct * 16 + q] = f2fh(acc[ct][j]);
        }
#pragma unroll
    for (int ct = 4; ct < 8; ++ct)
#pragma unroll
        for (int j = 0; j < 4; ++j) {
            const int gr = rowBase + wave * 16 + rg * 4 + j;
            if (gr < n)
                base[(size_t)gr * 64 + (ct - 4) * 16 + q] = acc[ct][j] + biasv[ct - 4];
        }
}

// ---------------- K2/K3: scans over blockcnt (bucket-major, in-place) --------
__global__ __launch_bounds__(BLK) void scan1(
    const int* __restrict__ cnt, int* __restrict__ offs,
    int* __restrict__ bsum, int n) {
    __shared__ int s[BLK];
    const int t = threadIdx.x;
    const int gid = blockIdx.x * BLK + t;
    const int v = (gid < n) ? cnt[gid] : 0;
    s[t] = v;
    __syncthreads();
#pragma unroll
    for (int o = 1; o < BLK; o <<= 1) {
        int u = (t >= o) ? s[t - o] : 0;
        __syncthreads();
        s[t] += u;
        __syncthreads();
    }
    if (gid < n) offs[gid] = s[t] - v;       // exclusive, block-local
    if (t == BLK - 1) bsum[blockIdx.x] = s[t];
}

__global__ __launch_bounds__(BLK) void scan23(
    int* __restrict__ offs, const int* __restrict__ bsum,
    int n, int total, int nb) {
    __shared__ int sb[BLK];
    const int t = threadIdx.x;
    const int v = (t < nb) ? bsum[t] : 0;
    sb[t] = v;
    __syncthreads();
#pragma unroll
    for (int o = 1; o < BLK; o <<= 1) {
        int u = (t >= o) ? sb[t - o] : 0;
        __syncthreads();
        sb[t] += u;
        __syncthreads();
    }
    sb[t] -= v;                               // exclusive
    __syncthreads();
    const int base = sb[blockIdx.x];
    const int gid = blockIdx.x * BLK + t;
    if (gid < n) offs[gid] += base;
    if (gid == 0) offs[n] = total;
}

// ---------------- K4: bucket write (exact positions, LDS rank) ---------------
__global__ __launch_bounds__(BLK) void bucket_write(
    const int* __restrict__ ei_raw, const int* __restrict__ boffs,
    uint2* __restrict__ tmp, int n_edges, int nbB, int nbBucket) {
    __shared__ int s_is64;
    __shared__ int bh[NBMAX];
    __shared__ int gbase[NBMAX];
    const int t = threadIdx.x;
    if (t == 0) {
        int all0 = 1;
        for (int i = 1; i < 128; i += 2) all0 &= (ei_raw[i] == 0);
        s_is64 = all0;
    }
    for (int b = t; b < NBMAX; b += BLK) bh[b] = 0;
    const int blk = blockIdx.x;
    for (int b = t; b < nbBucket; b += BLK)
        gbase[b] = boffs[(size_t)b * nbB + blk];
    __syncthreads();
    const int e0 = blk * EPB;
    const int is64 = s_is64;
    const long long* e64 = (const long long*)ei_raw;
#pragma unroll
    for (int i = 0; i < 32; ++i) {
        const int e = e0 + i * BLK + t;
        if (e < n_edges) {
            int s, d;
            if (is64) { s = (int)e64[e]; d = (int)e64[n_edges + e]; }
            else      { s = ei_raw[e];   d = ei_raw[n_edges + e]; }
            const int b = d >> DSH;
            const int r = atomicAdd(&bh[b], 1);        // LDS atomic only
            tmp[gbase[b] + r] = make_uint2((unsigned)s, (unsigned)d);
        }
    }
}

// ---------------- K5: bucket aggregation + finalize --------------------------
// One block per 128-dst bucket. LDS f32 accumulators (stride 65 -> 2-way
// banks); wave-per-edge, unroll 16. Self-loops seed the init; finalize does
// /den + base + ELU in-place on d_out.
__global__ __launch_bounds__(BLK) void bucket_agg(
    const uint2* __restrict__ tmp, const int* __restrict__ boffs,
    const unsigned short* __restrict__ h16,
    const float* __restrict__ a_src, const float* __restrict__ a_dst,
    float* __restrict__ out, int n_nodes, int n_edges, int nbB, int nbBucket) {
    __shared__ float accA[NPB * 65];   // 33,280 B
    __shared__ float denA[NPB * 5];    //  2,560 B
    __shared__ float adA[NPB * 5];     //  2,560 B
    const int b = blockIdx.x;
    const int dbase = b << DSH;
    const int ncount = min(NPB, n_nodes - dbase);
    const int t = threadIdx.x;
    const int bucket_base = boffs[(size_t)b * nbB];
    const int next_base = (b + 1 < nbBucket) ? boffs[(size_t)(b + 1) * nbB] : n_edges;
    const int cntb = next_base - bucket_base;

    // ---- init: 16-lane group per row; self-loop seeds accA/denA; stage adA
    const int g = t >> 4, q = t & 15, head = q >> 2;
    for (int row = g; row < ncount; row += 16) {
        const int dn = dbase + row;
        const float as = a_src[dn * 4 + head];
        const float ad = a_dst[dn * 4 + head];
        float e = as + ad;
        e = e > 0.f ? e : 0.2f * e;
        const float w = __expf(e);
        const ushort4 hp = *reinterpret_cast<const ushort4*>(
            h16 + (size_t)dn * 64 + q * 4);
        accA[row * 65 + q * 4 + 0] = w * fh2f(hp.x);
        accA[row * 65 + q * 4 + 1] = w * fh2f(hp.y);
        accA[row * 65 + q * 4 + 2] = w * fh2f(hp.z);
        accA[row * 65 + q * 4 + 3] = w * fh2f(hp.w);
        if ((q & 3) == 0) {
            denA[row * 5 + head] = w;
            adA[row * 5 + head] = ad;
        }
    }
    __syncthreads();

    // ---- edges: wave-per-edge, unroll 16 (64 edges in flight per block)
    const int wv = t >> 6, l = t & 63;
    const int hd = l >> 4;
    for (int i0 = wv * 16; i0 < cntb; i0 += 64) {
#pragma unroll
        for (int u = 0; u < 16; ++u) {
            const int i = i0 + u;
            if (i < cntb) {
                const uint2 p = tmp[bucket_base + i];
                const int s = (int)p.x;
                const int dl = (int)p.y - dbase;
                float e = a_src[s * 4 + hd] + adA[dl * 5 + hd];
                e = e > 0.f ? e : 0.2f * e;
                const float w = __expf(e);
                const float hv = fh2f(h16[(size_t)s * 64 + l]);
                atomicAdd(&accA[dl * 65 + l], w * hv);
                if ((l & 15) == 0) atomicAdd(&denA[dl * 5 + hd], w);
            }
        }
    }
    __syncthreads();

    // ---- finalize: /den + base + ELU, coalesced float4
    for (int row = g; row < ncount; row += 16) {
        const int dn = dbase + row;
        float* op = out + (size_t)dn * 64 + q * 4;
        const float4 bz = *reinterpret_cast<const float4*>(op);
        const float inv = 1.f / denA[row * 5 + head];
        float r0 = fmaf(accA[row * 65 + q * 4 + 0], inv, bz.x);
        float r1 = fmaf(accA[row * 65 + q * 4 + 1], inv, bz.y);
        float r2 = fmaf(accA[row * 65 + q * 4 + 2], inv, bz.z);
        float r3 = fmaf(accA[row * 65 + q * 4 + 3], inv, bz.w);
        float4 r;
        r.x = r0 > 0.f ? r0 : 0.1f * expm1f(r0);
        r.y = r1 > 0.f ? r1 : 0.1f * expm1f(r1);
        r.z = r2 > 0.f ? r2 : 0.1f * expm1f(r2);
        r.w = r3 > 0.f ? r3 : 0.1f * expm1f(r3);
        *reinterpret_cast<float4*>(op) = r;
    }
}

extern "C" void kernel_launch(void* const* d_in, const int* in_sizes, int n_in,
                              void* d_out, int out_size, void* d_ws, size_t ws_size,
                              hipStream_t stream) {
    const float* x         = (const float*)d_in[0];
    const int*   ei_raw    = (const int*)d_in[1];
    const float* W         = (const float*)d_in[2];
    const float* att_src   = (const float*)d_in[3];
    const float* att_dst   = (const float*)d_in[4];
    const float* conv_bias = (const float*)d_in[5];
    const float* skip_W    = (const float*)d_in[6];
    const float* skip_b    = (const float*)d_in[7];

    const int n_nodes = in_sizes[0] / 64;   // 50000
    const int n_edges = in_sizes[1] / 2;    // 800000

    const int nbNode = (n_nodes + 63) / 64;                 // 782
    const int nbB = (n_edges + EPB - 1) / EPB;              // 98
    const int nbBucket = (n_nodes + NPB - 1) / NPB;         // 391
    const int cntN = nbBucket * nbB;                        // 38318
    const int nb_c = (cntN + BLK - 1) / BLK;                // 150

    float* ws = (float*)d_ws;
    unsigned short* wfrag = (unsigned short*)ws;            // 8192 u16
    float* bias64 = ws + 4096;                              // 64
    float* watt_s = bias64 + 64;                            // 256
    float* watt_d = watt_s + 256;                           // 256
    uint2* tmp    = (uint2*)(watt_d + 256);                 // E uint2 (8B-aligned)
    unsigned short* h16 = (unsigned short*)(tmp + n_edges); // N*64 u16
    float* a_src  = (float*)(h16 + (size_t)n_nodes * 64);   // N*4
    float* a_dst  = a_src + (size_t)n_nodes * 4;            // N*4
    int*   blockcnt = (int*)(a_dst + (size_t)n_nodes * 4);  // cntN+1
    int*   bsum   = blockcnt + cntN + 1;                    // 256
    float* base   = (float*)d_out;

    prep_weights<<<1, BLK, 0, stream>>>(W, skip_W, conv_bias, skip_b,
                                        att_src, att_dst, wfrag, bias64,
                                        watt_s, watt_d);

    node_bcount<<<nbNode + nbB, BLK, 0, stream>>>(
        x, wfrag, bias64, watt_s, watt_d, h16, base, a_src, a_dst, n_nodes,
        ei_raw, blockcnt, n_edges, nbNode, nbB, nbBucket);

    scan1<<<nb_c, BLK, 0, stream>>>(blockcnt, blockcnt, bsum, cntN);
    scan23<<<nb_c, BLK, 0, stream>>>(blockcnt, bsum, cntN, n_edges, nb_c);

    bucket_write<<<nbB, BLK, 0, stream>>>(ei_raw, blockcnt, tmp,
                                          n_edges, nbB, nbBucket);

    bucket_agg<<<nbBucket, BLK, 0, stream>>>(tmp, blockcnt, h16, a_src, a_dst,
                                             (float*)d_out, n_nodes, n_edges,
                                             nbB, nbBucket);
}

// Round 13
// 93.043 us; speedup vs baseline: 4.9042x; 4.9042x over previous
//
#include <hip/hip_runtime.h>
#include <hip/hip_bf16.h>
#include <math.h>

// GAT block: N=50000, E=800000, H_IN=64, HEADS=4, C=16 (F=64 out)
// Round 13: revert to round-11 pipeline (r12's fused LDS-atomic aggregate had
// 391 blocks / 15% occupancy -> 410us). One change vs r11: scatter2 computes
// per-edge f16 softmax weights ONCE (a_dst LDS-staged) and writes a 16B
// payload {src,w01,w23,pad} at the sorted position (bucket-local, merged).
// Aggregate inner loop: uniform payload read + h16 gather + fma only.

#define BLK 256
#define NPB 512            // nodes per bucket
#define NBUCKET 128        // LDS bucket counters (98 used)
#define EPB 2048           // edges per bucketing block

typedef __attribute__((ext_vector_type(8))) short short8;
typedef __attribute__((ext_vector_type(4))) float f32x4;

static __device__ __forceinline__ unsigned short f2bf(float f) {
    union { float f; unsigned u; } v; v.f = f;
    return (unsigned short)((v.u + 0x7FFF + ((v.u >> 16) & 1)) >> 16);
}
static __device__ __forceinline__ unsigned short f2fh(float f) {
    union { _Float16 h; unsigned short u; } v; v.h = (_Float16)f; return v.u;
}
static __device__ __forceinline__ float fh2f(unsigned short u) {
    union { _Float16 h; unsigned short u; } v; v.u = u; return (float)v.h;
}

// ---------------- K0: pack weights + fold att vectors ------------------------
__global__ void prep_weights(const float* __restrict__ W,
                             const float* __restrict__ skipW,
                             const float* __restrict__ conv_bias,
                             const float* __restrict__ skip_b,
                             const float* __restrict__ att_src,
                             const float* __restrict__ att_dst,
                             unsigned short* __restrict__ wfrag,
                             float* __restrict__ bias64,
                             float* __restrict__ watt_s,
                             float* __restrict__ watt_d) {
    const int t = threadIdx.x;
    for (int idx = t; idx < 8192; idx += BLK) {
        const int j = idx & 7;
        const int lane = (idx >> 3) & 63;
        const int kh = (idx >> 9) & 1;
        const int ct = idx >> 10;
        const int k = kh * 32 + (lane >> 4) * 8 + j;
        const int c = ct * 16 + (lane & 15);
        const float v = (c < 64) ? W[k * 64 + c] : skipW[k * 64 + (c - 64)];
        wfrag[idx] = f2bf(v);
    }
    if (t < 64) bias64[t] = conv_bias[t] + skip_b[t];
    {   // t in [0,256): hh = t>>6, k = t&63
        const int hh = t >> 6, k = t & 63;
        float ssum = 0.f, dsum = 0.f;
#pragma unroll
        for (int c = 0; c < 16; ++c) {
            const float wv = W[k * 64 + hh * 16 + c];
            ssum = fmaf(wv, att_src[hh * 16 + c], ssum);
            dsum = fmaf(wv, att_dst[hh * 16 + c], dsum);
        }
        watt_s[hh * 64 + k] = ssum;
        watt_d[hh * 64 + k] = dsum;
    }
}

// ---------------- K1: fused node transform (MFMA) | bucket COUNT -------------
__global__ __launch_bounds__(BLK) void node_bcount(
    const float* __restrict__ x, const unsigned short* __restrict__ wfrag,
    const float* __restrict__ bias64, const float* __restrict__ watt_s,
    const float* __restrict__ watt_d,
    unsigned short* __restrict__ h16, float* __restrict__ base,
    float* __restrict__ a_src, float* __restrict__ a_dst, int n,
    const int* __restrict__ ei_raw, int* __restrict__ blockcnt,
    int n_edges, int nbNode, int nbB, int nbBucket) {
    __shared__ unsigned short sfrag[4 * 64 * 16];  // 8KB (node part)
    __shared__ float swatt[512];                   // 2KB (node part)
    __shared__ int s_is64;
    __shared__ int bh[NBUCKET];
    const int t = threadIdx.x;

    if (blockIdx.x >= nbNode) {   // ---------------- count part (dst only)
        if (t == 0) {
            int all0 = 1;
            for (int i = 1; i < 128; i += 2) all0 &= (ei_raw[i] == 0);
            s_is64 = all0;
        }
        if (t < NBUCKET) bh[t] = 0;
        __syncthreads();
        const int blk = blockIdx.x - nbNode;
        const int e0 = blk * EPB;
        const int is64 = s_is64;
        const long long* e64 = (const long long*)ei_raw;
#pragma unroll
        for (int i = 0; i < 8; ++i) {
            const int e = e0 + i * BLK + t;
            if (e < n_edges) {
                const int d = is64 ? (int)e64[n_edges + e] : ei_raw[n_edges + e];
                atomicAdd(&bh[d >> 9], 1);          // LDS atomic only
            }
        }
        __syncthreads();
        for (int b = t; b < nbBucket; b += BLK)
            blockcnt[(size_t)b * nbB + blk] = bh[b];
        return;
    }

    // ---------------- node transform part (unchanged)
    const int rowBase = blockIdx.x * 64;

    swatt[t] = watt_s[t];
    swatt[256 + t] = watt_d[t];

    const int r = t >> 2;
    const int c0 = (t & 3) << 4;
    const int grow = rowBase + r;
    float vals[16];
    if (grow < n) {
        const float4* xp = reinterpret_cast<const float4*>(x + (size_t)grow * 64 + c0);
        float4 a0 = xp[0], a1 = xp[1], a2 = xp[2], a3 = xp[3];
        vals[0]=a0.x; vals[1]=a0.y; vals[2]=a0.z; vals[3]=a0.w;
        vals[4]=a1.x; vals[5]=a1.y; vals[6]=a1.z; vals[7]=a1.w;
        vals[8]=a2.x; vals[9]=a2.y; vals[10]=a2.z; vals[11]=a2.w;
        vals[12]=a3.x; vals[13]=a3.y; vals[14]=a3.z; vals[15]=a3.w;
    } else {
#pragma unroll
        for (int i = 0; i < 16; ++i) vals[i] = 0.f;
    }

    {
        const int r15 = r & 15, wv = r >> 4;
#pragma unroll
        for (int oo = 0; oo < 2; ++oo) {
            const int oct = (t & 3) * 2 + oo;       // 0..7
            const int kh = oct >> 2, rg = oct & 3;
            const int lane = rg * 16 + r15;
            short8 p;
#pragma unroll
            for (int i = 0; i < 8; ++i) p[i] = (short)f2bf(vals[oo * 8 + i]);
            *reinterpret_cast<short8*>(&sfrag[((wv * 64 + lane) * 2 + kh) * 8]) = p;
        }
    }
    __syncthreads();

    {
#pragma unroll
        for (int hh = 0; hh < 4; ++hh) {
            float s = 0.f, dd = 0.f;
#pragma unroll
            for (int i = 0; i < 16; ++i) {
                s  = fmaf(vals[i], swatt[hh * 64 + c0 + i], s);
                dd = fmaf(vals[i], swatt[256 + hh * 64 + c0 + i], dd);
            }
            s  += __shfl_xor(s, 1);  s  += __shfl_xor(s, 2);
            dd += __shfl_xor(dd, 1); dd += __shfl_xor(dd, 2);
            if ((t & 3) == 0 && grow < n) {
                a_src[grow * 4 + hh] = s;
                a_dst[grow * 4 + hh] = dd;
            }
        }
    }

    const int wave = t >> 6, lane = t & 63;
    const int q = lane & 15, rg = lane >> 4;

    short8 bfr[8][2];
#pragma unroll
    for (int ct = 0; ct < 8; ++ct)
#pragma unroll
        for (int kh = 0; kh < 2; ++kh)
            bfr[ct][kh] = *reinterpret_cast<const short8*>(
                wfrag + (size_t)((ct * 2 + kh) * 64 + lane) * 8);

    short8 afr[2];
#pragma unroll
    for (int kh = 0; kh < 2; ++kh)
        afr[kh] = *reinterpret_cast<const short8*>(
            &sfrag[((wave * 64 + lane) * 2 + kh) * 8]);

    f32x4 acc[8];
#pragma unroll
    for (int i = 0; i < 8; ++i) { acc[i][0]=0.f; acc[i][1]=0.f; acc[i][2]=0.f; acc[i][3]=0.f; }
#pragma unroll
    for (int ct = 0; ct < 8; ++ct)
#pragma unroll
        for (int kh = 0; kh < 2; ++kh)
            acc[ct] = __builtin_amdgcn_mfma_f32_16x16x32_bf16(
                afr[kh], bfr[ct][kh], acc[ct], 0, 0, 0);

    float biasv[4];
#pragma unroll
    for (int i = 0; i < 4; ++i) biasv[i] = bias64[i * 16 + q];

#pragma unroll
    for (int ct = 0; ct < 4; ++ct)
#pragma unroll
        for (int j = 0; j < 4; ++j) {
            const int gr = rowBase + wave * 16 + rg * 4 + j;
            if (gr < n) h16[(size_t)gr * 64 + ct * 16 + q] = f2fh(acc[ct][j]);
        }
#pragma unroll
    for (int ct = 4; ct < 8; ++ct)
#pragma unroll
        for (int j = 0; j < 4; ++j) {
            const int gr = rowBase + wave * 16 + rg * 4 + j;
            if (gr < n)
                base[(size_t)gr * 64 + (ct - 4) * 16 + q] = acc[ct][j] + biasv[ct - 4];
        }
}

// ---------------- K2/K3: scans over blockcnt (bucket-major, in-place) --------
__global__ __launch_bounds__(BLK) void scan1(
    const int* __restrict__ cnt, int* __restrict__ offs,
    int* __restrict__ bsum, int n) {
    __shared__ int s[BLK];
    const int t = threadIdx.x;
    const int gid = blockIdx.x * BLK + t;
    const int v = (gid < n) ? cnt[gid] : 0;
    s[t] = v;
    __syncthreads();
#pragma unroll
    for (int o = 1; o < BLK; o <<= 1) {
        int u = (t >= o) ? s[t - o] : 0;
        __syncthreads();
        s[t] += u;
        __syncthreads();
    }
    if (gid < n) offs[gid] = s[t] - v;       // exclusive, block-local
    if (t == BLK - 1) bsum[blockIdx.x] = s[t];
}

__global__ __launch_bounds__(BLK) void scan23(
    int* __restrict__ offs, const int* __restrict__ bsum,
    int n, int total, int nb) {
    __shared__ int sb[BLK];
    const int t = threadIdx.x;
    const int v = (t < nb) ? bsum[t] : 0;
    sb[t] = v;
    __syncthreads();
#pragma unroll
    for (int o = 1; o < BLK; o <<= 1) {
        int u = (t >= o) ? sb[t - o] : 0;
        __syncthreads();
        sb[t] += u;
        __syncthreads();
    }
    sb[t] -= v;                               // exclusive
    __syncthreads();
    const int base = sb[blockIdx.x];
    const int gid = blockIdx.x * BLK + t;
    if (gid < n) offs[gid] += base;
    if (gid == 0) offs[n] = total;
}

// ---------------- K4: bucket write (exact positions, LDS rank) ---------------
__global__ __launch_bounds__(BLK) void bucket_write(
    const int* __restrict__ ei_raw, const int* __restrict__ boffs,
    uint2* __restrict__ tmp, int n_edges, int nbB, int nbBucket) {
    __shared__ int s_is64;
    __shared__ int bh[NBUCKET];
    __shared__ int gbase[NBUCKET];
    const int t = threadIdx.x;
    if (t == 0) {
        int all0 = 1;
        for (int i = 1; i < 128; i += 2) all0 &= (ei_raw[i] == 0);
        s_is64 = all0;
    }
    if (t < NBUCKET) bh[t] = 0;
    const int blk = blockIdx.x;
    for (int b = t; b < nbBucket; b += BLK)
        gbase[b] = boffs[(size_t)b * nbB + blk];
    __syncthreads();
    const int e0 = blk * EPB;
    const int is64 = s_is64;
    const long long* e64 = (const long long*)ei_raw;
#pragma unroll
    for (int i = 0; i < 8; ++i) {
        const int e = e0 + i * BLK + t;
        if (e < n_edges) {
            int s, d;
            if (is64) { s = (int)e64[e]; d = (int)e64[n_edges + e]; }
            else      { s = ei_raw[e];   d = ei_raw[n_edges + e]; }
            const int b = d >> 9;
            const int r = atomicAdd(&bh[b], 1);        // LDS atomic only
            tmp[gbase[b] + r] = make_uint2((unsigned)s, (unsigned)d);
        }
    }
}

// ---------------- K5: per-bucket sort + offs + f16 weight payload ------------
// One block per 512-node bucket. LDS histogram -> LDS pair scan -> coalesced
// offs write -> placement pass that ALSO computes the per-edge softmax
// weights once (a_dst staged in LDS) and writes a 16B payload at the sorted
// position (bucket-local region -> writes L2-merge).
__global__ __launch_bounds__(BLK) void scatter2(
    const uint2* __restrict__ tmp, const int* __restrict__ boffs,
    const float* __restrict__ a_src, const float* __restrict__ a_dst,
    int* __restrict__ offs, uint4* __restrict__ pay,
    int n_nodes, int n_edges, int nbB, int nbBucket) {
    __shared__ int lcnt[NPB];
    __shared__ int lofs[NPB];
    __shared__ int s2[BLK];
    __shared__ float sad[NPB * 4];     // a_dst rows of this bucket, 8KB
    const int b = blockIdx.x;
    const int dbase = b << 9;
    const int ncount = min(NPB, n_nodes - dbase);
    const int t = threadIdx.x;
    const int bucket_base = boffs[(size_t)b * nbB];
    const int next_base = (b + 1 < nbBucket) ? boffs[(size_t)(b + 1) * nbB] : n_edges;
    const int cntb = next_base - bucket_base;

    lcnt[t] = 0; lcnt[t + BLK] = 0;
    for (int idx = t; idx < ncount * 4; idx += BLK)
        sad[idx] = a_dst[dbase * 4 + idx];
    __syncthreads();
    const uint2* tb = tmp + bucket_base;
    for (int i = t; i < cntb; i += BLK)
        atomicAdd(&lcnt[(int)tb[i].y - dbase], 1);
    __syncthreads();

    // exclusive scan over 512 via 256 pair-sums
    s2[t] = lcnt[2 * t] + lcnt[2 * t + 1];
    __syncthreads();
#pragma unroll
    for (int o = 1; o < BLK; o <<= 1) {
        int u = (t >= o) ? s2[t - o] : 0;
        __syncthreads();
        s2[t] += u;
        __syncthreads();
    }
    const int pbase = (t > 0) ? s2[t - 1] : 0;   // exclusive pair prefix
    lofs[2 * t] = pbase;
    lofs[2 * t + 1] = pbase + lcnt[2 * t];
    __syncthreads();

    // offs (coalesced) + reset counters for the placement pass
    for (int k = t; k < ncount; k += BLK)
        offs[dbase + k] = bucket_base + lofs[k];
    if (b == nbBucket - 1 && t == 0) offs[n_nodes] = n_edges;
    lcnt[t] = 0; lcnt[t + BLK] = 0;
    __syncthreads();

    for (int i = t; i < cntb; i += BLK) {
        const uint2 p = tb[i];
        const int s = (int)p.x;
        const int dl = (int)p.y - dbase;
        const float4 as = *reinterpret_cast<const float4*>(a_src + (size_t)s * 4);
        float e0 = as.x + sad[dl * 4 + 0];
        float e1 = as.y + sad[dl * 4 + 1];
        float e2 = as.z + sad[dl * 4 + 2];
        float e3 = as.w + sad[dl * 4 + 3];
        e0 = e0 > 0.f ? e0 : 0.2f * e0;
        e1 = e1 > 0.f ? e1 : 0.2f * e1;
        e2 = e2 > 0.f ? e2 : 0.2f * e2;
        e3 = e3 > 0.f ? e3 : 0.2f * e3;
        uint4 o;
        o.x = (unsigned)s;
        o.y = (unsigned)f2fh(__expf(e0)) | ((unsigned)f2fh(__expf(e1)) << 16);
        o.z = (unsigned)f2fh(__expf(e2)) | ((unsigned)f2fh(__expf(e3)) << 16);
        o.w = 0;
        const int pos = bucket_base + lofs[dl] + atomicAdd(&lcnt[dl], 1);
        pay[pos] = o;
    }
}

// ---------------- K6: gather aggregation + finalize --------------------------
// 16-lane group per dst node (16 nodes/block). Inner loop: uniform 16B
// payload broadcast + coalesced h16 quad gather + fma. No exp, no a-gather.
// Per-feature summation order identical to r8/r11 (sequential sorted order).
__global__ __launch_bounds__(BLK) void aggregate_kernel(
    const uint4* __restrict__ pay, const int* __restrict__ offs,
    const unsigned short* __restrict__ h16,
    const float* __restrict__ a_src, const float* __restrict__ a_dst,
    float* __restrict__ out, int n_nodes) {
    const int g = threadIdx.x >> 4;          // group in block: 0..15
    const int q = threadIdx.x & 15;          // lane in group
    const int d = blockIdx.x * 16 + g;
    if (d >= n_nodes) return;
    const int head = q >> 2;
    const int beg = offs[d], end = offs[d + 1];

    // self-loop seed (exact f32 logits)
    float e = a_src[d * 4 + head] + a_dst[d * 4 + head];
    e = e > 0.f ? e : 0.2f * e;
    const float w = __expf(e);
    float den = w;
    float acc0, acc1, acc2, acc3;
    {
        const ushort4 hp = *reinterpret_cast<const ushort4*>(
            h16 + (size_t)d * 64 + q * 4);
        acc0 = w * fh2f(hp.x); acc1 = w * fh2f(hp.y);
        acc2 = w * fh2f(hp.z); acc3 = w * fh2f(hp.w);
    }

#pragma unroll 4
    for (int j = beg; j < end; ++j) {
        const uint4 p = pay[j];                          // uniform per group
        const unsigned pair = (head & 2) ? p.z : p.y;
        const unsigned short wu =
            (head & 1) ? (unsigned short)(pair >> 16) : (unsigned short)(pair & 0xffffu);
        const float ww = fh2f(wu);
        const ushort4 hp = *reinterpret_cast<const ushort4*>(
            h16 + (size_t)(int)p.x * 64 + q * 4);
        acc0 = fmaf(ww, fh2f(hp.x), acc0);
        acc1 = fmaf(ww, fh2f(hp.y), acc1);
        acc2 = fmaf(ww, fh2f(hp.z), acc2);
        acc3 = fmaf(ww, fh2f(hp.w), acc3);
        den += ww;
    }

    float* op = out + (size_t)d * 64 + q * 4;
    const float4 b = *reinterpret_cast<const float4*>(op);
    const float inv = 1.f / den;
    float r0 = fmaf(acc0, inv, b.x);
    float r1 = fmaf(acc1, inv, b.y);
    float r2 = fmaf(acc2, inv, b.z);
    float r3 = fmaf(acc3, inv, b.w);
    float4 r;
    r.x = r0 > 0.f ? r0 : 0.1f * expm1f(r0);
    r.y = r1 > 0.f ? r1 : 0.1f * expm1f(r1);
    r.z = r2 > 0.f ? r2 : 0.1f * expm1f(r2);
    r.w = r3 > 0.f ? r3 : 0.1f * expm1f(r3);
    *reinterpret_cast<float4*>(op) = r;
}

extern "C" void kernel_launch(void* const* d_in, const int* in_sizes, int n_in,
                              void* d_out, int out_size, void* d_ws, size_t ws_size,
                              hipStream_t stream) {
    const float* x         = (const float*)d_in[0];
    const int*   ei_raw    = (const int*)d_in[1];
    const float* W         = (const float*)d_in[2];
    const float* att_src   = (const float*)d_in[3];
    const float* att_dst   = (const float*)d_in[4];
    const float* conv_bias = (const float*)d_in[5];
    const float* skip_W    = (const float*)d_in[6];
    const float* skip_b    = (const float*)d_in[7];

    const int n_nodes = in_sizes[0] / 64;   // 50000
    const int n_edges = in_sizes[1] / 2;    // 800000

    const int nbNode = (n_nodes + 63) / 64;                 // 782
    const int nbB = (n_edges + EPB - 1) / EPB;              // 391
    const int nbBucket = (n_nodes + NPB - 1) / NPB;         // 98
    const int cntN = nbBucket * nbB;                        // 38318
    const int nb_c = (cntN + BLK - 1) / BLK;                // 150

    float* ws = (float*)d_ws;
    unsigned short* wfrag = (unsigned short*)ws;            // 8192 u16 = 16KB
    float* bias64 = ws + 4096;                              // 64
    float* watt_s = bias64 + 64;                            // 256
    float* watt_d = watt_s + 256;                           // 256
    uint4* pay    = (uint4*)(watt_d + 256);                 // E uint4 (16B-aligned)
    uint2* tmp    = (uint2*)(pay + n_edges);                // E uint2
    unsigned short* h16 = (unsigned short*)(tmp + n_edges); // N*64 u16
    float* a_src  = (float*)(h16 + (size_t)n_nodes * 64);   // N*4
    float* a_dst  = a_src + (size_t)n_nodes * 4;            // N*4
    int*   blockcnt = (int*)(a_dst + (size_t)n_nodes * 4);  // cntN+1
    int*   bsum   = blockcnt + cntN + 1;                    // 256
    int*   offs   = bsum + 256;                             // N+1
    float* base   = (float*)d_out;

    prep_weights<<<1, BLK, 0, stream>>>(W, skip_W, conv_bias, skip_b,
                                        att_src, att_dst, wfrag, bias64,
                                        watt_s, watt_d);

    node_bcount<<<nbNode + nbB, BLK, 0, stream>>>(
        x, wfrag, bias64, watt_s, watt_d, h16, base, a_src, a_dst, n_nodes,
        ei_raw, blockcnt, n_edges, nbNode, nbB, nbBucket);

    scan1<<<nb_c, BLK, 0, stream>>>(blockcnt, blockcnt, bsum, cntN);
    scan23<<<nb_c, BLK, 0, stream>>>(blockcnt, bsum, cntN, n_edges, nb_c);

    bucket_write<<<nbB, BLK, 0, stream>>>(ei_raw, blockcnt, tmp,
                                          n_edges, nbB, nbBucket);
    scatter2<<<nbBucket, BLK, 0, stream>>>(tmp, blockcnt, a_src, a_dst,
                                           offs, pay, n_nodes, n_edges,
                                           nbB, nbBucket);

    aggregate_kernel<<<(n_nodes + 15) / 16, BLK, 0, stream>>>(
        pay, offs, h16, a_src, a_dst, (float*)d_out, n_nodes);
}

// Round 14
// 80.134 us; speedup vs baseline: 5.6943x; 1.1611x over previous
//
#include <hip/hip_runtime.h>
#include <hip/hip_bf16.h>
#include <math.h>

// GAT block: N=50000, E=800000, H_IN=64, HEADS=4, C=16 (F=64 out)
// Round 14: revert to round-11 pipeline (r13's payload precompute added
// 25MB of traffic to save free VALU -> regression). One change vs r11:
// aggregate uses 8-lane groups (ushort8 h-loads, 32 nodes/block, 2x edge
// chains in flight). Per-feature summation order identical to r11.

#define BLK 256
#define NPB 512            // nodes per bucket
#define NBUCKET 128        // LDS bucket counters (98 used)
#define EPB 2048           // edges per bucketing block

typedef __attribute__((ext_vector_type(8))) short short8;
typedef __attribute__((ext_vector_type(4))) float f32x4;

static __device__ __forceinline__ unsigned short f2bf(float f) {
    union { float f; unsigned u; } v; v.f = f;
    return (unsigned short)((v.u + 0x7FFF + ((v.u >> 16) & 1)) >> 16);
}
static __device__ __forceinline__ unsigned short f2fh(float f) {
    union { _Float16 h; unsigned short u; } v; v.h = (_Float16)f; return v.u;
}
static __device__ __forceinline__ float fh2f(unsigned short u) {
    union { _Float16 h; unsigned short u; } v; v.u = u; return (float)v.h;
}

// ---------------- K0: pack weights + fold att vectors ------------------------
__global__ void prep_weights(const float* __restrict__ W,
                             const float* __restrict__ skipW,
                             const float* __restrict__ conv_bias,
                             const float* __restrict__ skip_b,
                             const float* __restrict__ att_src,
                             const float* __restrict__ att_dst,
                             unsigned short* __restrict__ wfrag,
                             float* __restrict__ bias64,
                             float* __restrict__ watt_s,
                             float* __restrict__ watt_d) {
    const int t = threadIdx.x;
    for (int idx = t; idx < 8192; idx += BLK) {
        const int j = idx & 7;
        const int lane = (idx >> 3) & 63;
        const int kh = (idx >> 9) & 1;
        const int ct = idx >> 10;
        const int k = kh * 32 + (lane >> 4) * 8 + j;
        const int c = ct * 16 + (lane & 15);
        const float v = (c < 64) ? W[k * 64 + c] : skipW[k * 64 + (c - 64)];
        wfrag[idx] = f2bf(v);
    }
    if (t < 64) bias64[t] = conv_bias[t] + skip_b[t];
    {   // t in [0,256): hh = t>>6, k = t&63
        const int hh = t >> 6, k = t & 63;
        float ssum = 0.f, dsum = 0.f;
#pragma unroll
        for (int c = 0; c < 16; ++c) {
            const float wv = W[k * 64 + hh * 16 + c];
            ssum = fmaf(wv, att_src[hh * 16 + c], ssum);
            dsum = fmaf(wv, att_dst[hh * 16 + c], dsum);
        }
        watt_s[hh * 64 + k] = ssum;
        watt_d[hh * 64 + k] = dsum;
    }
}

// ---------------- K1: fused node transform (MFMA) | bucket COUNT -------------
__global__ __launch_bounds__(BLK) void node_bcount(
    const float* __restrict__ x, const unsigned short* __restrict__ wfrag,
    const float* __restrict__ bias64, const float* __restrict__ watt_s,
    const float* __restrict__ watt_d,
    unsigned short* __restrict__ h16, float* __restrict__ base,
    float* __restrict__ a_src, float* __restrict__ a_dst, int n,
    const int* __restrict__ ei_raw, int* __restrict__ blockcnt,
    int n_edges, int nbNode, int nbB, int nbBucket) {
    __shared__ unsigned short sfrag[4 * 64 * 16];  // 8KB (node part)
    __shared__ float swatt[512];                   // 2KB (node part)
    __shared__ int s_is64;
    __shared__ int bh[NBUCKET];
    const int t = threadIdx.x;

    if (blockIdx.x >= nbNode) {   // ---------------- count part (dst only)
        if (t == 0) {
            int all0 = 1;
            for (int i = 1; i < 128; i += 2) all0 &= (ei_raw[i] == 0);
            s_is64 = all0;
        }
        if (t < NBUCKET) bh[t] = 0;
        __syncthreads();
        const int blk = blockIdx.x - nbNode;
        const int e0 = blk * EPB;
        const int is64 = s_is64;
        const long long* e64 = (const long long*)ei_raw;
#pragma unroll
        for (int i = 0; i < 8; ++i) {
            const int e = e0 + i * BLK + t;
            if (e < n_edges) {
                const int d = is64 ? (int)e64[n_edges + e] : ei_raw[n_edges + e];
                atomicAdd(&bh[d >> 9], 1);          // LDS atomic only
            }
        }
        __syncthreads();
        for (int b = t; b < nbBucket; b += BLK)
            blockcnt[(size_t)b * nbB + blk] = bh[b];
        return;
    }

    // ---------------- node transform part (unchanged)
    const int rowBase = blockIdx.x * 64;

    swatt[t] = watt_s[t];
    swatt[256 + t] = watt_d[t];

    const int r = t >> 2;
    const int c0 = (t & 3) << 4;
    const int grow = rowBase + r;
    float vals[16];
    if (grow < n) {
        const float4* xp = reinterpret_cast<const float4*>(x + (size_t)grow * 64 + c0);
        float4 a0 = xp[0], a1 = xp[1], a2 = xp[2], a3 = xp[3];
        vals[0]=a0.x; vals[1]=a0.y; vals[2]=a0.z; vals[3]=a0.w;
        vals[4]=a1.x; vals[5]=a1.y; vals[6]=a1.z; vals[7]=a1.w;
        vals[8]=a2.x; vals[9]=a2.y; vals[10]=a2.z; vals[11]=a2.w;
        vals[12]=a3.x; vals[13]=a3.y; vals[14]=a3.z; vals[15]=a3.w;
    } else {
#pragma unroll
        for (int i = 0; i < 16; ++i) vals[i] = 0.f;
    }

    {
        const int r15 = r & 15, wv = r >> 4;
#pragma unroll
        for (int oo = 0; oo < 2; ++oo) {
            const int oct = (t & 3) * 2 + oo;       // 0..7
            const int kh = oct >> 2, rg = oct & 3;
            const int lane = rg * 16 + r15;
            short8 p;
#pragma unroll
            for (int i = 0; i < 8; ++i) p[i] = (short)f2bf(vals[oo * 8 + i]);
            *reinterpret_cast<short8*>(&sfrag[((wv * 64 + lane) * 2 + kh) * 8]) = p;
        }
    }
    __syncthreads();

    {
#pragma unroll
        for (int hh = 0; hh < 4; ++hh) {
            float s = 0.f, dd = 0.f;
#pragma unroll
            for (int i = 0; i < 16; ++i) {
                s  = fmaf(vals[i], swatt[hh * 64 + c0 + i], s);
                dd = fmaf(vals[i], swatt[256 + hh * 64 + c0 + i], dd);
            }
            s  += __shfl_xor(s, 1);  s  += __shfl_xor(s, 2);
            dd += __shfl_xor(dd, 1); dd += __shfl_xor(dd, 2);
            if ((t & 3) == 0 && grow < n) {
                a_src[grow * 4 + hh] = s;
                a_dst[grow * 4 + hh] = dd;
            }
        }
    }

    const int wave = t >> 6, lane = t & 63;
    const int q = lane & 15, rg = lane >> 4;

    short8 bfr[8][2];
#pragma unroll
    for (int ct = 0; ct < 8; ++ct)
#pragma unroll
        for (int kh = 0; kh < 2; ++kh)
            bfr[ct][kh] = *reinterpret_cast<const short8*>(
                wfrag + (size_t)((ct * 2 + kh) * 64 + lane) * 8);

    short8 afr[2];
#pragma unroll
    for (int kh = 0; kh < 2; ++kh)
        afr[kh] = *reinterpret_cast<const short8*>(
            &sfrag[((wave * 64 + lane) * 2 + kh) * 8]);

    f32x4 acc[8];
#pragma unroll
    for (int i = 0; i < 8; ++i) { acc[i][0]=0.f; acc[i][1]=0.f; acc[i][2]=0.f; acc[i][3]=0.f; }
#pragma unroll
    for (int ct = 0; ct < 8; ++ct)
#pragma unroll
        for (int kh = 0; kh < 2; ++kh)
            acc[ct] = __builtin_amdgcn_mfma_f32_16x16x32_bf16(
                afr[kh], bfr[ct][kh], acc[ct], 0, 0, 0);

    float biasv[4];
#pragma unroll
    for (int i = 0; i < 4; ++i) biasv[i] = bias64[i * 16 + q];

#pragma unroll
    for (int ct = 0; ct < 4; ++ct)
#pragma unroll
        for (int j = 0; j < 4; ++j) {
            const int gr = rowBase + wave * 16 + rg * 4 + j;
            if (gr < n) h16[(size_t)gr * 64 + ct * 16 + q] = f2fh(acc[ct][j]);
        }
#pragma unroll
    for (int ct = 4; ct < 8; ++ct)
#pragma unroll
        for (int j = 0; j < 4; ++j) {
            const int gr = rowBase + wave * 16 + rg * 4 + j;
            if (gr < n)
                base[(size_t)gr * 64 + (ct - 4) * 16 + q] = acc[ct][j] + biasv[ct - 4];
        }
}

// ---------------- K2/K3: scans over blockcnt (bucket-major, in-place) --------
__global__ __launch_bounds__(BLK) void scan1(
    const int* __restrict__ cnt, int* __restrict__ offs,
    int* __restrict__ bsum, int n) {
    __shared__ int s[BLK];
    const int t = threadIdx.x;
    const int gid = blockIdx.x * BLK + t;
    const int v = (gid < n) ? cnt[gid] : 0;
    s[t] = v;
    __syncthreads();
#pragma unroll
    for (int o = 1; o < BLK; o <<= 1) {
        int u = (t >= o) ? s[t - o] : 0;
        __syncthreads();
        s[t] += u;
        __syncthreads();
    }
    if (gid < n) offs[gid] = s[t] - v;       // exclusive, block-local
    if (t == BLK - 1) bsum[blockIdx.x] = s[t];
}

__global__ __launch_bounds__(BLK) void scan23(
    int* __restrict__ offs, const int* __restrict__ bsum,
    int n, int total, int nb) {
    __shared__ int sb[BLK];
    const int t = threadIdx.x;
    const int v = (t < nb) ? bsum[t] : 0;
    sb[t] = v;
    __syncthreads();
#pragma unroll
    for (int o = 1; o < BLK; o <<= 1) {
        int u = (t >= o) ? sb[t - o] : 0;
        __syncthreads();
        sb[t] += u;
        __syncthreads();
    }
    sb[t] -= v;                               // exclusive
    __syncthreads();
    const int base = sb[blockIdx.x];
    const int gid = blockIdx.x * BLK + t;
    if (gid < n) offs[gid] += base;
    if (gid == 0) offs[n] = total;
}

// ---------------- K4: bucket write (exact positions, LDS rank) ---------------
__global__ __launch_bounds__(BLK) void bucket_write(
    const int* __restrict__ ei_raw, const int* __restrict__ boffs,
    uint2* __restrict__ tmp, int n_edges, int nbB, int nbBucket) {
    __shared__ int s_is64;
    __shared__ int bh[NBUCKET];
    __shared__ int gbase[NBUCKET];
    const int t = threadIdx.x;
    if (t == 0) {
        int all0 = 1;
        for (int i = 1; i < 128; i += 2) all0 &= (ei_raw[i] == 0);
        s_is64 = all0;
    }
    if (t < NBUCKET) bh[t] = 0;
    const int blk = blockIdx.x;
    for (int b = t; b < nbBucket; b += BLK)
        gbase[b] = boffs[(size_t)b * nbB + blk];
    __syncthreads();
    const int e0 = blk * EPB;
    const int is64 = s_is64;
    const long long* e64 = (const long long*)ei_raw;
#pragma unroll
    for (int i = 0; i < 8; ++i) {
        const int e = e0 + i * BLK + t;
        if (e < n_edges) {
            int s, d;
            if (is64) { s = (int)e64[e]; d = (int)e64[n_edges + e]; }
            else      { s = ei_raw[e];   d = ei_raw[n_edges + e]; }
            const int b = d >> 9;
            const int r = atomicAdd(&bh[b], 1);        // LDS atomic only
            tmp[gbase[b] + r] = make_uint2((unsigned)s, (unsigned)d);
        }
    }
}

// ---------------- K5: per-bucket sort + offs production ----------------------
__global__ __launch_bounds__(BLK) void scatter2(
    const uint2* __restrict__ tmp, const int* __restrict__ boffs,
    int* __restrict__ offs, int* __restrict__ sorted_src,
    int n_nodes, int n_edges, int nbB, int nbBucket) {
    __shared__ int lcnt[NPB];
    __shared__ int lofs[NPB];
    __shared__ int s2[BLK];
    const int b = blockIdx.x;
    const int dbase = b << 9;
    const int ncount = min(NPB, n_nodes - dbase);
    const int t = threadIdx.x;
    const int bucket_base = boffs[(size_t)b * nbB];
    const int next_base = (b + 1 < nbBucket) ? boffs[(size_t)(b + 1) * nbB] : n_edges;
    const int cntb = next_base - bucket_base;

    lcnt[t] = 0; lcnt[t + BLK] = 0;
    __syncthreads();
    const uint2* tb = tmp + bucket_base;
    for (int i = t; i < cntb; i += BLK)
        atomicAdd(&lcnt[(int)tb[i].y - dbase], 1);
    __syncthreads();

    // exclusive scan over 512 via 256 pair-sums
    s2[t] = lcnt[2 * t] + lcnt[2 * t + 1];
    __syncthreads();
#pragma unroll
    for (int o = 1; o < BLK; o <<= 1) {
        int u = (t >= o) ? s2[t - o] : 0;
        __syncthreads();
        s2[t] += u;
        __syncthreads();
    }
    const int pbase = (t > 0) ? s2[t - 1] : 0;   // exclusive pair prefix
    lofs[2 * t] = pbase;
    lofs[2 * t + 1] = pbase + lcnt[2 * t];
    __syncthreads();

    // offs (coalesced) + reset counters for the placement pass
    for (int k = t; k < ncount; k += BLK)
        offs[dbase + k] = bucket_base + lofs[k];
    if (b == nbBucket - 1 && t == 0) offs[n_nodes] = n_edges;
    lcnt[t] = 0; lcnt[t + BLK] = 0;
    __syncthreads();

    for (int i = t; i < cntb; i += BLK) {
        const uint2 p = tb[i];
        const int dl = (int)p.y - dbase;
        const int pos = bucket_base + lofs[dl] + atomicAdd(&lcnt[dl], 1);
        sorted_src[pos] = (int)p.x;
    }
}

// ---------------- K6: gather aggregation + finalize --------------------------
// 8-lane group per dst node (32 nodes/block). Lane q owns features
// q*8..q*8+7 loaded as one ushort8 (16B); a group's h-row = one 128B line.
// head = q>>1. Per-feature summation order identical to rounds 8-11.
__global__ __launch_bounds__(BLK) void aggregate_kernel(
    const int* __restrict__ sorted_src, const int* __restrict__ offs,
    const unsigned short* __restrict__ h16,
    const float* __restrict__ a_src, const float* __restrict__ a_dst,
    float* __restrict__ out, int n_nodes) {
    const int g = threadIdx.x >> 3;          // group in block: 0..31
    const int q = threadIdx.x & 7;           // lane in group
    const int d = blockIdx.x * 32 + g;
    if (d >= n_nodes) return;
    const int head = q >> 1;
    const float ad = a_dst[d * 4 + head];
    const int beg = offs[d], end = offs[d + 1];

    float accv[8];
    float den;
    {   // self-loop seed
        float e = a_src[d * 4 + head] + ad;
        e = e > 0.f ? e : 0.2f * e;
        const float w = __expf(e);
        den = w;
        const short8 hp = *reinterpret_cast<const short8*>(
            h16 + (size_t)d * 64 + q * 8);
#pragma unroll
        for (int i = 0; i < 8; ++i)
            accv[i] = w * fh2f((unsigned short)hp[i]);
    }

#pragma unroll 4
    for (int j = beg; j < end; ++j) {
        const int s = sorted_src[j];
        float es = a_src[s * 4 + head] + ad;
        es = es > 0.f ? es : 0.2f * es;
        const float ww = __expf(es);
        const short8 hp = *reinterpret_cast<const short8*>(
            h16 + (size_t)s * 64 + q * 8);
#pragma unroll
        for (int i = 0; i < 8; ++i)
            accv[i] = fmaf(ww, fh2f((unsigned short)hp[i]), accv[i]);
        den += ww;
    }

    float* op = out + (size_t)d * 64 + q * 8;
    const float4 b0 = *reinterpret_cast<const float4*>(op);
    const float4 b1 = *reinterpret_cast<const float4*>(op + 4);
    const float inv = 1.f / den;
    float rr[8];
    rr[0] = fmaf(accv[0], inv, b0.x); rr[1] = fmaf(accv[1], inv, b0.y);
    rr[2] = fmaf(accv[2], inv, b0.z); rr[3] = fmaf(accv[3], inv, b0.w);
    rr[4] = fmaf(accv[4], inv, b1.x); rr[5] = fmaf(accv[5], inv, b1.y);
    rr[6] = fmaf(accv[6], inv, b1.z); rr[7] = fmaf(accv[7], inv, b1.w);
#pragma unroll
    for (int i = 0; i < 8; ++i)
        rr[i] = rr[i] > 0.f ? rr[i] : 0.1f * expm1f(rr[i]);
    float4 r0, r1;
    r0.x = rr[0]; r0.y = rr[1]; r0.z = rr[2]; r0.w = rr[3];
    r1.x = rr[4]; r1.y = rr[5]; r1.z = rr[6]; r1.w = rr[7];
    *reinterpret_cast<float4*>(op) = r0;
    *reinterpret_cast<float4*>(op + 4) = r1;
}

extern "C" void kernel_launch(void* const* d_in, const int* in_sizes, int n_in,
                              void* d_out, int out_size, void* d_ws, size_t ws_size,
                              hipStream_t stream) {
    const float* x         = (const float*)d_in[0];
    const int*   ei_raw    = (const int*)d_in[1];
    const float* W         = (const float*)d_in[2];
    const float* att_src   = (const float*)d_in[3];
    const float* att_dst   = (const float*)d_in[4];
    const float* conv_bias = (const float*)d_in[5];
    const float* skip_W    = (const float*)d_in[6];
    const float* skip_b    = (const float*)d_in[7];

    const int n_nodes = in_sizes[0] / 64;   // 50000
    const int n_edges = in_sizes[1] / 2;    // 800000

    const int nbNode = (n_nodes + 63) / 64;                 // 782
    const int nbB = (n_edges + EPB - 1) / EPB;              // 391
    const int nbBucket = (n_nodes + NPB - 1) / NPB;         // 98
    const int cntN = nbBucket * nbB;                        // 38318
    const int nb_c = (cntN + BLK - 1) / BLK;                // 150

    float* ws = (float*)d_ws;
    unsigned short* wfrag = (unsigned short*)ws;            // 8192 u16
    float* bias64 = ws + 4096;                              // 64
    float* watt_s = bias64 + 64;                            // 256
    float* watt_d = watt_s + 256;                           // 256
    uint2* tmp    = (uint2*)(watt_d + 256);                 // E uint2 (8B-aligned)
    unsigned short* h16 = (unsigned short*)(tmp + n_edges); // N*64 u16
    float* a_src  = (float*)(h16 + (size_t)n_nodes * 64);   // N*4
    float* a_dst  = a_src + (size_t)n_nodes * 4;            // N*4
    int*   blockcnt = (int*)(a_dst + (size_t)n_nodes * 4);  // cntN+1
    int*   bsum   = blockcnt + cntN + 1;                    // 256
    int*   offs   = bsum + 256;                             // N+1
    int*   sorted_src = offs + n_nodes + 1;                 // E
    float* base   = (float*)d_out;

    prep_weights<<<1, BLK, 0, stream>>>(W, skip_W, conv_bias, skip_b,
                                        att_src, att_dst, wfrag, bias64,
                                        watt_s, watt_d);

    node_bcount<<<nbNode + nbB, BLK, 0, stream>>>(
        x, wfrag, bias64, watt_s, watt_d, h16, base, a_src, a_dst, n_nodes,
        ei_raw, blockcnt, n_edges, nbNode, nbB, nbBucket);

    scan1<<<nb_c, BLK, 0, stream>>>(blockcnt, blockcnt, bsum, cntN);
    scan23<<<nb_c, BLK, 0, stream>>>(blockcnt, bsum, cntN, n_edges, nb_c);

    bucket_write<<<nbB, BLK, 0, stream>>>(ei_raw, blockcnt, tmp,
                                          n_edges, nbB, nbBucket);
    scatter2<<<nbBucket, BLK, 0, stream>>>(tmp, blockcnt, offs, sorted_src,
                                           n_nodes, n_edges, nbB, nbBucket);

    aggregate_kernel<<<(n_nodes + 31) / 32, BLK, 0, stream>>>(
        sorted_src, offs, h16, a_src, a_dst, (float*)d_out, n_nodes);
}

// Round 15
// 73.646 us; speedup vs baseline: 6.1959x; 1.0881x over previous
//
#include <hip/hip_runtime.h>
#include <hip/hip_bf16.h>
#include <math.h>

// GAT block: N=50000, E=800000, H_IN=64, HEADS=4, C=16 (F=64 out)
// Round 15: sort collapsed to 4 kernels. Node kernel's bucket blocks do
// LDS-rank + one global reservation atomic per (block,bucket) (38k total —
// r10 proved these are harmless; its 800k per-edge cnt atomics were the
// 52MB writeback) and write dense uint2 runs into BCAP-padded tmp.
// scans/bucket_write deleted; scatter2 scans the 98-entry bcur in LDS for
// its global base. Aggregate byte-identical to round 14.

#define BLK 256
#define NPB 512            // nodes per bucket
#define NBUCKET 128        // LDS counters (98 used)
#define BCAP 16384         // tmp slots per bucket (mean 8163, sigma~90)
#define EPB 2048           // edges per bucketing block (8/thread)

typedef __attribute__((ext_vector_type(8))) short short8;
typedef __attribute__((ext_vector_type(4))) float f32x4;

static __device__ __forceinline__ unsigned short f2bf(float f) {
    union { float f; unsigned u; } v; v.f = f;
    return (unsigned short)((v.u + 0x7FFF + ((v.u >> 16) & 1)) >> 16);
}
static __device__ __forceinline__ unsigned short f2fh(float f) {
    union { _Float16 h; unsigned short u; } v; v.h = (_Float16)f; return v.u;
}
static __device__ __forceinline__ float fh2f(unsigned short u) {
    union { _Float16 h; unsigned short u; } v; v.u = u; return (float)v.h;
}

// ---------------- K0: pack weights + fold att vectors + zero bcur ------------
__global__ void prep_weights(const float* __restrict__ W,
                             const float* __restrict__ skipW,
                             const float* __restrict__ conv_bias,
                             const float* __restrict__ skip_b,
                             const float* __restrict__ att_src,
                             const float* __restrict__ att_dst,
                             unsigned short* __restrict__ wfrag,
                             float* __restrict__ bias64,
                             float* __restrict__ watt_s,
                             float* __restrict__ watt_d,
                             int* __restrict__ bcur) {
    const int t = threadIdx.x;
    for (int idx = t; idx < 8192; idx += BLK) {
        const int j = idx & 7;
        const int lane = (idx >> 3) & 63;
        const int kh = (idx >> 9) & 1;
        const int ct = idx >> 10;
        const int k = kh * 32 + (lane >> 4) * 8 + j;
        const int c = ct * 16 + (lane & 15);
        const float v = (c < 64) ? W[k * 64 + c] : skipW[k * 64 + (c - 64)];
        wfrag[idx] = f2bf(v);
    }
    if (t < 64) bias64[t] = conv_bias[t] + skip_b[t];
    if (t < NBUCKET) bcur[t] = 0;
    {   // t in [0,256): hh = t>>6, k = t&63
        const int hh = t >> 6, k = t & 63;
        float ssum = 0.f, dsum = 0.f;
#pragma unroll
        for (int c = 0; c < 16; ++c) {
            const float wv = W[k * 64 + hh * 16 + c];
            ssum = fmaf(wv, att_src[hh * 16 + c], ssum);
            dsum = fmaf(wv, att_dst[hh * 16 + c], dsum);
        }
        watt_s[hh * 64 + k] = ssum;
        watt_d[hh * 64 + k] = dsum;
    }
}

// ---------------- K1: fused node transform (MFMA) | edge bucketing -----------
// Blocks [0, nbNode): node transform. Blocks [nbNode, nbNode+nbB): read EPB
// edges once, LDS-rank per bucket, one reservation atomic per (block,bucket),
// write dense uint2 {s,d} runs into tmp[b*BCAP + ...].
__global__ __launch_bounds__(BLK) void node_bucket(
    const float* __restrict__ x, const unsigned short* __restrict__ wfrag,
    const float* __restrict__ bias64, const float* __restrict__ watt_s,
    const float* __restrict__ watt_d,
    unsigned short* __restrict__ h16, float* __restrict__ base,
    float* __restrict__ a_src, float* __restrict__ a_dst, int n,
    const int* __restrict__ ei_raw, int* __restrict__ bcur,
    uint2* __restrict__ tmp, int n_edges, int nbNode) {
    __shared__ unsigned short sfrag[4 * 64 * 16];  // 8KB (node part)
    __shared__ float swatt[512];                   // 2KB (node part)
    __shared__ int s_is64;
    __shared__ int bh[NBUCKET];                    // bucket part
    __shared__ int gb[NBUCKET];
    const int t = threadIdx.x;

    if (blockIdx.x >= nbNode) {   // ---------------- bucket part
        if (t == 0) {
            int all0 = 1;
            for (int i = 1; i < 128; i += 2) all0 &= (ei_raw[i] == 0);
            s_is64 = all0;
        }
        if (t < NBUCKET) bh[t] = 0;
        __syncthreads();
        const int e0 = (blockIdx.x - nbNode) * EPB;
        const int is64 = s_is64;
        const long long* e64 = (const long long*)ei_raw;
        int sarr[8], darr[8], rarr[8];
#pragma unroll
        for (int i = 0; i < 8; ++i) {
            const int e = e0 + i * BLK + t;
            if (e < n_edges) {
                if (is64) {
                    sarr[i] = (int)e64[e];
                    darr[i] = (int)e64[n_edges + e];
                } else {
                    sarr[i] = ei_raw[e];
                    darr[i] = ei_raw[n_edges + e];
                }
            } else darr[i] = -1;
        }
#pragma unroll
        for (int i = 0; i < 8; ++i)
            if (darr[i] >= 0) rarr[i] = atomicAdd(&bh[darr[i] >> 9], 1);
        __syncthreads();
        if (t < NBUCKET && bh[t] > 0) gb[t] = atomicAdd(&bcur[t], bh[t]);
        __syncthreads();
#pragma unroll
        for (int i = 0; i < 8; ++i) {
            if (darr[i] >= 0) {
                const int b = darr[i] >> 9;
                const int r = gb[b] + rarr[i];
                if (r < BCAP)
                    tmp[(size_t)b * BCAP + r] =
                        make_uint2((unsigned)sarr[i], (unsigned)darr[i]);
            }
        }
        return;
    }

    // ---------------- node transform part (unchanged)
    const int rowBase = blockIdx.x * 64;

    swatt[t] = watt_s[t];
    swatt[256 + t] = watt_d[t];

    const int r = t >> 2;
    const int c0 = (t & 3) << 4;
    const int grow = rowBase + r;
    float vals[16];
    if (grow < n) {
        const float4* xp = reinterpret_cast<const float4*>(x + (size_t)grow * 64 + c0);
        float4 a0 = xp[0], a1 = xp[1], a2 = xp[2], a3 = xp[3];
        vals[0]=a0.x; vals[1]=a0.y; vals[2]=a0.z; vals[3]=a0.w;
        vals[4]=a1.x; vals[5]=a1.y; vals[6]=a1.z; vals[7]=a1.w;
        vals[8]=a2.x; vals[9]=a2.y; vals[10]=a2.z; vals[11]=a2.w;
        vals[12]=a3.x; vals[13]=a3.y; vals[14]=a3.z; vals[15]=a3.w;
    } else {
#pragma unroll
        for (int i = 0; i < 16; ++i) vals[i] = 0.f;
    }

    {
        const int r15 = r & 15, wv = r >> 4;
#pragma unroll
        for (int oo = 0; oo < 2; ++oo) {
            const int oct = (t & 3) * 2 + oo;       // 0..7
            const int kh = oct >> 2, rg = oct & 3;
            const int lane = rg * 16 + r15;
            short8 p;
#pragma unroll
            for (int i = 0; i < 8; ++i) p[i] = (short)f2bf(vals[oo * 8 + i]);
            *reinterpret_cast<short8*>(&sfrag[((wv * 64 + lane) * 2 + kh) * 8]) = p;
        }
    }
    __syncthreads();

    {
#pragma unroll
        for (int hh = 0; hh < 4; ++hh) {
            float s = 0.f, dd = 0.f;
#pragma unroll
            for (int i = 0; i < 16; ++i) {
                s  = fmaf(vals[i], swatt[hh * 64 + c0 + i], s);
                dd = fmaf(vals[i], swatt[256 + hh * 64 + c0 + i], dd);
            }
            s  += __shfl_xor(s, 1);  s  += __shfl_xor(s, 2);
            dd += __shfl_xor(dd, 1); dd += __shfl_xor(dd, 2);
            if ((t & 3) == 0 && grow < n) {
                a_src[grow * 4 + hh] = s;
                a_dst[grow * 4 + hh] = dd;
            }
        }
    }

    const int wave = t >> 6, lane = t & 63;
    const int q = lane & 15, rg = lane >> 4;

    short8 bfr[8][2];
#pragma unroll
    for (int ct = 0; ct < 8; ++ct)
#pragma unroll
        for (int kh = 0; kh < 2; ++kh)
            bfr[ct][kh] = *reinterpret_cast<const short8*>(
                wfrag + (size_t)((ct * 2 + kh) * 64 + lane) * 8);

    short8 afr[2];
#pragma unroll
    for (int kh = 0; kh < 2; ++kh)
        afr[kh] = *reinterpret_cast<const short8*>(
            &sfrag[((wave * 64 + lane) * 2 + kh) * 8]);

    f32x4 acc[8];
#pragma unroll
    for (int i = 0; i < 8; ++i) { acc[i][0]=0.f; acc[i][1]=0.f; acc[i][2]=0.f; acc[i][3]=0.f; }
#pragma unroll
    for (int ct = 0; ct < 8; ++ct)
#pragma unroll
        for (int kh = 0; kh < 2; ++kh)
            acc[ct] = __builtin_amdgcn_mfma_f32_16x16x32_bf16(
                afr[kh], bfr[ct][kh], acc[ct], 0, 0, 0);

    float biasv[4];
#pragma unroll
    for (int i = 0; i < 4; ++i) biasv[i] = bias64[i * 16 + q];

#pragma unroll
    for (int ct = 0; ct < 4; ++ct)
#pragma unroll
        for (int j = 0; j < 4; ++j) {
            const int gr = rowBase + wave * 16 + rg * 4 + j;
            if (gr < n) h16[(size_t)gr * 64 + ct * 16 + q] = f2fh(acc[ct][j]);
        }
#pragma unroll
    for (int ct = 4; ct < 8; ++ct)
#pragma unroll
        for (int j = 0; j < 4; ++j) {
            const int gr = rowBase + wave * 16 + rg * 4 + j;
            if (gr < n)
                base[(size_t)gr * 64 + (ct - 4) * 16 + q] = acc[ct][j] + biasv[ct - 4];
        }
}

// ---------------- K2: per-bucket sort + offs production ----------------------
// One block per bucket. Global base = exclusive prefix of bcur (98 entries,
// scanned in LDS). Then: LDS per-node histogram -> pair scan -> coalesced
// offs write -> placement pass into dense sorted_src.
__global__ __launch_bounds__(BLK) void scatter2(
    const uint2* __restrict__ tmp, const int* __restrict__ bcur,
    int* __restrict__ offs, int* __restrict__ sorted_src,
    int n_nodes, int n_edges, int nbBucket) {
    __shared__ int lcnt[NPB];
    __shared__ int lofs[NPB];
    __shared__ int s2[BLK];
    __shared__ int sp[NBUCKET];
    const int b = blockIdx.x;
    const int dbase = b << 9;
    const int ncount = min(NPB, n_nodes - dbase);
    const int t = threadIdx.x;

    // inclusive scan of bcur over NBUCKET entries (first 128 threads)
    if (t < NBUCKET) sp[t] = (t < nbBucket) ? bcur[t] : 0;
    __syncthreads();
#pragma unroll
    for (int o = 1; o < NBUCKET; o <<= 1) {
        int u = (t >= o && t < NBUCKET) ? sp[t - o] : 0;
        __syncthreads();
        if (t < NBUCKET) sp[t] += u;
        __syncthreads();
    }
    const int bucket_base = (b > 0) ? sp[b - 1] : 0;
    const int cntb = sp[b] - bucket_base;

    lcnt[t] = 0; lcnt[t + BLK] = 0;
    __syncthreads();
    const uint2* tb = tmp + (size_t)b * BCAP;
    for (int i = t; i < cntb; i += BLK)
        atomicAdd(&lcnt[(int)tb[i].y - dbase], 1);
    __syncthreads();

    // exclusive scan over 512 via 256 pair-sums
    s2[t] = lcnt[2 * t] + lcnt[2 * t + 1];
    __syncthreads();
#pragma unroll
    for (int o = 1; o < BLK; o <<= 1) {
        int u = (t >= o) ? s2[t - o] : 0;
        __syncthreads();
        s2[t] += u;
        __syncthreads();
    }
    const int pbase = (t > 0) ? s2[t - 1] : 0;   // exclusive pair prefix
    lofs[2 * t] = pbase;
    lofs[2 * t + 1] = pbase + lcnt[2 * t];
    __syncthreads();

    // offs (coalesced) + reset counters for the placement pass
    for (int k = t; k < ncount; k += BLK)
        offs[dbase + k] = bucket_base + lofs[k];
    if (b == nbBucket - 1 && t == 0) offs[n_nodes] = n_edges;
    lcnt[t] = 0; lcnt[t + BLK] = 0;
    __syncthreads();

    for (int i = t; i < cntb; i += BLK) {
        const uint2 p = tb[i];
        const int dl = (int)p.y - dbase;
        const int pos = bucket_base + lofs[dl] + atomicAdd(&lcnt[dl], 1);
        sorted_src[pos] = (int)p.x;
    }
}

// ---------------- K3: gather aggregation + finalize (round-14 verbatim) ------
// 8-lane group per dst node (32 nodes/block). Lane q owns features
// q*8..q*8+7 loaded as one ushort8; head = q>>1.
__global__ __launch_bounds__(BLK) void aggregate_kernel(
    const int* __restrict__ sorted_src, const int* __restrict__ offs,
    const unsigned short* __restrict__ h16,
    const float* __restrict__ a_src, const float* __restrict__ a_dst,
    float* __restrict__ out, int n_nodes) {
    const int g = threadIdx.x >> 3;          // group in block: 0..31
    const int q = threadIdx.x & 7;           // lane in group
    const int d = blockIdx.x * 32 + g;
    if (d >= n_nodes) return;
    const int head = q >> 1;
    const float ad = a_dst[d * 4 + head];
    const int beg = offs[d], end = offs[d + 1];

    float accv[8];
    float den;
    {   // self-loop seed
        float e = a_src[d * 4 + head] + ad;
        e = e > 0.f ? e : 0.2f * e;
        const float w = __expf(e);
        den = w;
        const short8 hp = *reinterpret_cast<const short8*>(
            h16 + (size_t)d * 64 + q * 8);
#pragma unroll
        for (int i = 0; i < 8; ++i)
            accv[i] = w * fh2f((unsigned short)hp[i]);
    }

#pragma unroll 4
    for (int j = beg; j < end; ++j) {
        const int s = sorted_src[j];
        float es = a_src[s * 4 + head] + ad;
        es = es > 0.f ? es : 0.2f * es;
        const float ww = __expf(es);
        const short8 hp = *reinterpret_cast<const short8*>(
            h16 + (size_t)s * 64 + q * 8);
#pragma unroll
        for (int i = 0; i < 8; ++i)
            accv[i] = fmaf(ww, fh2f((unsigned short)hp[i]), accv[i]);
        den += ww;
    }

    float* op = out + (size_t)d * 64 + q * 8;
    const float4 b0 = *reinterpret_cast<const float4*>(op);
    const float4 b1 = *reinterpret_cast<const float4*>(op + 4);
    const float inv = 1.f / den;
    float rr[8];
    rr[0] = fmaf(accv[0], inv, b0.x); rr[1] = fmaf(accv[1], inv, b0.y);
    rr[2] = fmaf(accv[2], inv, b0.z); rr[3] = fmaf(accv[3], inv, b0.w);
    rr[4] = fmaf(accv[4], inv, b1.x); rr[5] = fmaf(accv[5], inv, b1.y);
    rr[6] = fmaf(accv[6], inv, b1.z); rr[7] = fmaf(accv[7], inv, b1.w);
#pragma unroll
    for (int i = 0; i < 8; ++i)
        rr[i] = rr[i] > 0.f ? rr[i] : 0.1f * expm1f(rr[i]);
    float4 r0, r1;
    r0.x = rr[0]; r0.y = rr[1]; r0.z = rr[2]; r0.w = rr[3];
    r1.x = rr[4]; r1.y = rr[5]; r1.z = rr[6]; r1.w = rr[7];
    *reinterpret_cast<float4*>(op) = r0;
    *reinterpret_cast<float4*>(op + 4) = r1;
}

extern "C" void kernel_launch(void* const* d_in, const int* in_sizes, int n_in,
                              void* d_out, int out_size, void* d_ws, size_t ws_size,
                              hipStream_t stream) {
    const float* x         = (const float*)d_in[0];
    const int*   ei_raw    = (const int*)d_in[1];
    const float* W         = (const float*)d_in[2];
    const float* att_src   = (const float*)d_in[3];
    const float* att_dst   = (const float*)d_in[4];
    const float* conv_bias = (const float*)d_in[5];
    const float* skip_W    = (const float*)d_in[6];
    const float* skip_b    = (const float*)d_in[7];

    const int n_nodes = in_sizes[0] / 64;   // 50000
    const int n_edges = in_sizes[1] / 2;    // 800000

    const int nbNode = (n_nodes + 63) / 64;                 // 782
    const int nbB = (n_edges + EPB - 1) / EPB;              // 391
    const int nbBucket = (n_nodes + NPB - 1) / NPB;         // 98

    float* ws = (float*)d_ws;
    unsigned short* wfrag = (unsigned short*)ws;            // 8192 u16
    float* bias64 = ws + 4096;                              // 64
    float* watt_s = bias64 + 64;                            // 256
    float* watt_d = watt_s + 256;                           // 256
    int*   bcur   = (int*)(watt_d + 256);                   // NBUCKET
    uint2* tmp    = (uint2*)(bcur + NBUCKET);               // NBUCKET*BCAP uint2
    unsigned short* h16 = (unsigned short*)(tmp + (size_t)NBUCKET * BCAP); // N*64
    float* a_src  = (float*)(h16 + (size_t)n_nodes * 64);   // N*4
    float* a_dst  = a_src + (size_t)n_nodes * 4;            // N*4
    int*   offs   = (int*)(a_dst + (size_t)n_nodes * 4);    // N+1
    int*   sorted_src = offs + n_nodes + 1;                 // E
    float* base   = (float*)d_out;

    prep_weights<<<1, BLK, 0, stream>>>(W, skip_W, conv_bias, skip_b,
                                        att_src, att_dst, wfrag, bias64,
                                        watt_s, watt_d, bcur);

    node_bucket<<<nbNode + nbB, BLK, 0, stream>>>(
        x, wfrag, bias64, watt_s, watt_d, h16, base, a_src, a_dst, n_nodes,
        ei_raw, bcur, tmp, n_edges, nbNode);

    scatter2<<<nbBucket, BLK, 0, stream>>>(tmp, bcur, offs, sorted_src,
                                           n_nodes, n_edges, nbBucket);

    aggregate_kernel<<<(n_nodes + 31) / 32, BLK, 0, stream>>>(
        sorted_src, offs, h16, a_src, a_dst, (float*)d_out, n_nodes);
}

// Round 17
// 73.161 us; speedup vs baseline: 6.2370x; 1.0066x over previous
//
#include <hip/hip_runtime.h>
#include <hip/hip_bf16.h>
#include <math.h>

// GAT block: N=50000, E=800000, H_IN=64, HEADS=4, C=16 (F=64 out)
// Round 17: revert to round-15 (proven 73.6us). Round-16's cooperative
// launch never executed (absmax == empty-stub signature) — cooperative
// kernels don't survive this harness's graph capture; 4-launch pipeline
// is the structural floor.
//
// Pipeline: prep | node-MFMA∥bucket (1 edge read, LDS-rank + per-(block,
// bucket) reservation) | per-bucket sort->offs/sorted_src | gather-aggregate.

#define BLK 256
#define NPB 512            // nodes per bucket
#define NBUCKET 128        // LDS counters (98 used)
#define BCAP 16384         // tmp slots per bucket (mean 8163, sigma~90)
#define EPB 2048           // edges per bucketing block (8/thread)

typedef __attribute__((ext_vector_type(8))) short short8;
typedef __attribute__((ext_vector_type(4))) float f32x4;

static __device__ __forceinline__ unsigned short f2bf(float f) {
    union { float f; unsigned u; } v; v.f = f;
    return (unsigned short)((v.u + 0x7FFF + ((v.u >> 16) & 1)) >> 16);
}
static __device__ __forceinline__ unsigned short f2fh(float f) {
    union { _Float16 h; unsigned short u; } v; v.h = (_Float16)f; return v.u;
}
static __device__ __forceinline__ float fh2f(unsigned short u) {
    union { _Float16 h; unsigned short u; } v; v.u = u; return (float)v.h;
}

// ---------------- K0: pack weights + fold att vectors + zero bcur ------------
__global__ void prep_weights(const float* __restrict__ W,
                             const float* __restrict__ skipW,
                             const float* __restrict__ conv_bias,
                             const float* __restrict__ skip_b,
                             const float* __restrict__ att_src,
                             const float* __restrict__ att_dst,
                             unsigned short* __restrict__ wfrag,
                             float* __restrict__ bias64,
                             float* __restrict__ watt_s,
                             float* __restrict__ watt_d,
                             int* __restrict__ bcur) {
    const int t = threadIdx.x;
    for (int idx = t; idx < 8192; idx += BLK) {
        const int j = idx & 7;
        const int lane = (idx >> 3) & 63;
        const int kh = (idx >> 9) & 1;
        const int ct = idx >> 10;
        const int k = kh * 32 + (lane >> 4) * 8 + j;
        const int c = ct * 16 + (lane & 15);
        const float v = (c < 64) ? W[k * 64 + c] : skipW[k * 64 + (c - 64)];
        wfrag[idx] = f2bf(v);
    }
    if (t < 64) bias64[t] = conv_bias[t] + skip_b[t];
    if (t < NBUCKET) bcur[t] = 0;
    {   // t in [0,256): hh = t>>6, k = t&63
        const int hh = t >> 6, k = t & 63;
        float ssum = 0.f, dsum = 0.f;
#pragma unroll
        for (int c = 0; c < 16; ++c) {
            const float wv = W[k * 64 + hh * 16 + c];
            ssum = fmaf(wv, att_src[hh * 16 + c], ssum);
            dsum = fmaf(wv, att_dst[hh * 16 + c], dsum);
        }
        watt_s[hh * 64 + k] = ssum;
        watt_d[hh * 64 + k] = dsum;
    }
}

// ---------------- K1: fused node transform (MFMA) | edge bucketing -----------
// Blocks [0, nbNode): node transform. Blocks [nbNode, nbNode+nbB): read EPB
// edges once, LDS-rank per bucket, one reservation atomic per (block,bucket),
// write dense uint2 {s,d} runs into tmp[b*BCAP + ...].
__global__ __launch_bounds__(BLK) void node_bucket(
    const float* __restrict__ x, const unsigned short* __restrict__ wfrag,
    const float* __restrict__ bias64, const float* __restrict__ watt_s,
    const float* __restrict__ watt_d,
    unsigned short* __restrict__ h16, float* __restrict__ base,
    float* __restrict__ a_src, float* __restrict__ a_dst, int n,
    const int* __restrict__ ei_raw, int* __restrict__ bcur,
    uint2* __restrict__ tmp, int n_edges, int nbNode) {
    __shared__ unsigned short sfrag[4 * 64 * 16];  // 8KB (node part)
    __shared__ float swatt[512];                   // 2KB (node part)
    __shared__ int s_is64;
    __shared__ int bh[NBUCKET];                    // bucket part
    __shared__ int gb[NBUCKET];
    const int t = threadIdx.x;

    if (blockIdx.x >= nbNode) {   // ---------------- bucket part
        if (t == 0) {
            int all0 = 1;
            for (int i = 1; i < 128; i += 2) all0 &= (ei_raw[i] == 0);
            s_is64 = all0;
        }
        if (t < NBUCKET) bh[t] = 0;
        __syncthreads();
        const int e0 = (blockIdx.x - nbNode) * EPB;
        const int is64 = s_is64;
        const long long* e64 = (const long long*)ei_raw;
        int sarr[8], darr[8], rarr[8];
#pragma unroll
        for (int i = 0; i < 8; ++i) {
            const int e = e0 + i * BLK + t;
            if (e < n_edges) {
                if (is64) {
                    sarr[i] = (int)e64[e];
                    darr[i] = (int)e64[n_edges + e];
                } else {
                    sarr[i] = ei_raw[e];
                    darr[i] = ei_raw[n_edges + e];
                }
            } else darr[i] = -1;
        }
#pragma unroll
        for (int i = 0; i < 8; ++i)
            if (darr[i] >= 0) rarr[i] = atomicAdd(&bh[darr[i] >> 9], 1);
        __syncthreads();
        if (t < NBUCKET && bh[t] > 0) gb[t] = atomicAdd(&bcur[t], bh[t]);
        __syncthreads();
#pragma unroll
        for (int i = 0; i < 8; ++i) {
            if (darr[i] >= 0) {
                const int b = darr[i] >> 9;
                const int r = gb[b] + rarr[i];
                if (r < BCAP)
                    tmp[(size_t)b * BCAP + r] =
                        make_uint2((unsigned)sarr[i], (unsigned)darr[i]);
            }
        }
        return;
    }

    // ---------------- node transform part
    const int rowBase = blockIdx.x * 64;

    swatt[t] = watt_s[t];
    swatt[256 + t] = watt_d[t];

    const int r = t >> 2;
    const int c0 = (t & 3) << 4;
    const int grow = rowBase + r;
    float vals[16];
    if (grow < n) {
        const float4* xp = reinterpret_cast<const float4*>(x + (size_t)grow * 64 + c0);
        float4 a0 = xp[0], a1 = xp[1], a2 = xp[2], a3 = xp[3];
        vals[0]=a0.x; vals[1]=a0.y; vals[2]=a0.z; vals[3]=a0.w;
        vals[4]=a1.x; vals[5]=a1.y; vals[6]=a1.z; vals[7]=a1.w;
        vals[8]=a2.x; vals[9]=a2.y; vals[10]=a2.z; vals[11]=a2.w;
        vals[12]=a3.x; vals[13]=a3.y; vals[14]=a3.z; vals[15]=a3.w;
    } else {
#pragma unroll
        for (int i = 0; i < 16; ++i) vals[i] = 0.f;
    }

    {
        const int r15 = r & 15, wv = r >> 4;
#pragma unroll
        for (int oo = 0; oo < 2; ++oo) {
            const int oct = (t & 3) * 2 + oo;       // 0..7
            const int kh = oct >> 2, rg = oct & 3;
            const int lane = rg * 16 + r15;
            short8 p;
#pragma unroll
            for (int i = 0; i < 8; ++i) p[i] = (short)f2bf(vals[oo * 8 + i]);
            *reinterpret_cast<short8*>(&sfrag[((wv * 64 + lane) * 2 + kh) * 8]) = p;
        }
    }
    __syncthreads();

    {
#pragma unroll
        for (int hh = 0; hh < 4; ++hh) {
            float s = 0.f, dd = 0.f;
#pragma unroll
            for (int i = 0; i < 16; ++i) {
                s  = fmaf(vals[i], swatt[hh * 64 + c0 + i], s);
                dd = fmaf(vals[i], swatt[256 + hh * 64 + c0 + i], dd);
            }
            s  += __shfl_xor(s, 1);  s  += __shfl_xor(s, 2);
            dd += __shfl_xor(dd, 1); dd += __shfl_xor(dd, 2);
            if ((t & 3) == 0 && grow < n) {
                a_src[grow * 4 + hh] = s;
                a_dst[grow * 4 + hh] = dd;
            }
        }
    }

    const int wave = t >> 6, lane = t & 63;
    const int q = lane & 15, rg = lane >> 4;

    short8 bfr[8][2];
#pragma unroll
    for (int ct = 0; ct < 8; ++ct)
#pragma unroll
        for (int kh = 0; kh < 2; ++kh)
            bfr[ct][kh] = *reinterpret_cast<const short8*>(
                wfrag + (size_t)((ct * 2 + kh) * 64 + lane) * 8);

    short8 afr[2];
#pragma unroll
    for (int kh = 0; kh < 2; ++kh)
        afr[kh] = *reinterpret_cast<const short8*>(
            &sfrag[((wave * 64 + lane) * 2 + kh) * 8]);

    f32x4 acc[8];
#pragma unroll
    for (int i = 0; i < 8; ++i) { acc[i][0]=0.f; acc[i][1]=0.f; acc[i][2]=0.f; acc[i][3]=0.f; }
#pragma unroll
    for (int ct = 0; ct < 8; ++ct)
#pragma unroll
        for (int kh = 0; kh < 2; ++kh)
            acc[ct] = __builtin_amdgcn_mfma_f32_16x16x32_bf16(
                afr[kh], bfr[ct][kh], acc[ct], 0, 0, 0);

    float biasv[4];
#pragma unroll
    for (int i = 0; i < 4; ++i) biasv[i] = bias64[i * 16 + q];

#pragma unroll
    for (int ct = 0; ct < 4; ++ct)
#pragma unroll
        for (int j = 0; j < 4; ++j) {
            const int gr = rowBase + wave * 16 + rg * 4 + j;
            if (gr < n) h16[(size_t)gr * 64 + ct * 16 + q] = f2fh(acc[ct][j]);
        }
#pragma unroll
    for (int ct = 4; ct < 8; ++ct)
#pragma unroll
        for (int j = 0; j < 4; ++j) {
            const int gr = rowBase + wave * 16 + rg * 4 + j;
            if (gr < n)
                base[(size_t)gr * 64 + (ct - 4) * 16 + q] = acc[ct][j] + biasv[ct - 4];
        }
}

// ---------------- K2: per-bucket sort + offs production ----------------------
// One block per bucket. Global base = exclusive prefix of bcur (98 entries,
// scanned in LDS). Then: LDS per-node histogram -> pair scan -> coalesced
// offs write -> placement pass into dense sorted_src.
__global__ __launch_bounds__(BLK) void scatter2(
    const uint2* __restrict__ tmp, const int* __restrict__ bcur,
    int* __restrict__ offs, int* __restrict__ sorted_src,
    int n_nodes, int n_edges, int nbBucket) {
    __shared__ int lcnt[NPB];
    __shared__ int lofs[NPB];
    __shared__ int s2[BLK];
    __shared__ int sp[NBUCKET];
    const int b = blockIdx.x;
    const int dbase = b << 9;
    const int ncount = min(NPB, n_nodes - dbase);
    const int t = threadIdx.x;

    // inclusive scan of bcur over NBUCKET entries (first 128 threads)
    if (t < NBUCKET) sp[t] = (t < nbBucket) ? bcur[t] : 0;
    __syncthreads();
#pragma unroll
    for (int o = 1; o < NBUCKET; o <<= 1) {
        int u = (t >= o && t < NBUCKET) ? sp[t - o] : 0;
        __syncthreads();
        if (t < NBUCKET) sp[t] += u;
        __syncthreads();
    }
    const int bucket_base = (b > 0) ? sp[b - 1] : 0;
    const int cntb = sp[b] - bucket_base;

    lcnt[t] = 0; lcnt[t + BLK] = 0;
    __syncthreads();
    const uint2* tb = tmp + (size_t)b * BCAP;
    for (int i = t; i < cntb; i += BLK)
        atomicAdd(&lcnt[(int)tb[i].y - dbase], 1);
    __syncthreads();

    // exclusive scan over 512 via 256 pair-sums
    s2[t] = lcnt[2 * t] + lcnt[2 * t + 1];
    __syncthreads();
#pragma unroll
    for (int o = 1; o < BLK; o <<= 1) {
        int u = (t >= o) ? s2[t - o] : 0;
        __syncthreads();
        s2[t] += u;
        __syncthreads();
    }
    const int pbase = (t > 0) ? s2[t - 1] : 0;   // exclusive pair prefix
    lofs[2 * t] = pbase;
    lofs[2 * t + 1] = pbase + lcnt[2 * t];
    __syncthreads();

    // offs (coalesced) + reset counters for the placement pass
    for (int k = t; k < ncount; k += BLK)
        offs[dbase + k] = bucket_base + lofs[k];
    if (b == nbBucket - 1 && t == 0) offs[n_nodes] = n_edges;
    lcnt[t] = 0; lcnt[t + BLK] = 0;
    __syncthreads();

    for (int i = t; i < cntb; i += BLK) {
        const uint2 p = tb[i];
        const int dl = (int)p.y - dbase;
        const int pos = bucket_base + lofs[dl] + atomicAdd(&lcnt[dl], 1);
        sorted_src[pos] = (int)p.x;
    }
}

// ---------------- K3: gather aggregation + finalize --------------------------
// 8-lane group per dst node (32 nodes/block). Lane q owns features
// q*8..q*8+7 loaded as one ushort8; head = q>>1.
__global__ __launch_bounds__(BLK) void aggregate_kernel(
    const int* __restrict__ sorted_src, const int* __restrict__ offs,
    const unsigned short* __restrict__ h16,
    const float* __restrict__ a_src, const float* __restrict__ a_dst,
    float* __restrict__ out, int n_nodes) {
    const int g = threadIdx.x >> 3;          // group in block: 0..31
    const int q = threadIdx.x & 7;           // lane in group
    const int d = blockIdx.x * 32 + g;
    if (d >= n_nodes) return;
    const int head = q >> 1;
    const float ad = a_dst[d * 4 + head];
    const int beg = offs[d], end = offs[d + 1];

    float accv[8];
    float den;
    {   // self-loop seed
        float e = a_src[d * 4 + head] + ad;
        e = e > 0.f ? e : 0.2f * e;
        const float w = __expf(e);
        den = w;
        const short8 hp = *reinterpret_cast<const short8*>(
            h16 + (size_t)d * 64 + q * 8);
#pragma unroll
        for (int i = 0; i < 8; ++i)
            accv[i] = w * fh2f((unsigned short)hp[i]);
    }

#pragma unroll 4
    for (int j = beg; j < end; ++j) {
        const int s = sorted_src[j];
        float es = a_src[s * 4 + head] + ad;
        es = es > 0.f ? es : 0.2f * es;
        const float ww = __expf(es);
        const short8 hp = *reinterpret_cast<const short8*>(
            h16 + (size_t)s * 64 + q * 8);
#pragma unroll
        for (int i = 0; i < 8; ++i)
            accv[i] = fmaf(ww, fh2f((unsigned short)hp[i]), accv[i]);
        den += ww;
    }

    float* op = out + (size_t)d * 64 + q * 8;
    const float4 b0 = *reinterpret_cast<const float4*>(op);
    const float4 b1 = *reinterpret_cast<const float4*>(op + 4);
    const float inv = 1.f / den;
    float rr[8];
    rr[0] = fmaf(accv[0], inv, b0.x); rr[1] = fmaf(accv[1], inv, b0.y);
    rr[2] = fmaf(accv[2], inv, b0.z); rr[3] = fmaf(accv[3], inv, b0.w);
    rr[4] = fmaf(accv[4], inv, b1.x); rr[5] = fmaf(accv[5], inv, b1.y);
    rr[6] = fmaf(accv[6], inv, b1.z); rr[7] = fmaf(accv[7], inv, b1.w);
#pragma unroll
    for (int i = 0; i < 8; ++i)
        rr[i] = rr[i] > 0.f ? rr[i] : 0.1f * expm1f(rr[i]);
    float4 r0, r1;
    r0.x = rr[0]; r0.y = rr[1]; r0.z = rr[2]; r0.w = rr[3];
    r1.x = rr[4]; r1.y = rr[5]; r1.z = rr[6]; r1.w = rr[7];
    *reinterpret_cast<float4*>(op) = r0;
    *reinterpret_cast<float4*>(op + 4) = r1;
}

extern "C" void kernel_launch(void* const* d_in, const int* in_sizes, int n_in,
                              void* d_out, int out_size, void* d_ws, size_t ws_size,
                              hipStream_t stream) {
    const float* x         = (const float*)d_in[0];
    const int*   ei_raw    = (const int*)d_in[1];
    const float* W         = (const float*)d_in[2];
    const float* att_src   = (const float*)d_in[3];
    const float* att_dst   = (const float*)d_in[4];
    const float* conv_bias = (const float*)d_in[5];
    const float* skip_W    = (const float*)d_in[6];
    const float* skip_b    = (const float*)d_in[7];

    const int n_nodes = in_sizes[0] / 64;   // 50000
    const int n_edges = in_sizes[1] / 2;    // 800000

    const int nbNode = (n_nodes + 63) / 64;                 // 782
    const int nbB = (n_edges + EPB - 1) / EPB;              // 391
    const int nbBucket = (n_nodes + NPB - 1) / NPB;         // 98

    float* ws = (float*)d_ws;
    unsigned short* wfrag = (unsigned short*)ws;            // 8192 u16
    float* bias64 = ws + 4096;                              // 64
    float* watt_s = bias64 + 64;                            // 256
    float* watt_d = watt_s + 256;                           // 256
    int*   bcur   = (int*)(watt_d + 256);                   // NBUCKET
    uint2* tmp    = (uint2*)(bcur + NBUCKET);               // NBUCKET*BCAP uint2
    unsigned short* h16 = (unsigned short*)(tmp + (size_t)NBUCKET * BCAP); // N*64
    float* a_src  = (float*)(h16 + (size_t)n_nodes * 64);   // N*4
    float* a_dst  = a_src + (size_t)n_nodes * 4;            // N*4
    int*   offs   = (int*)(a_dst + (size_t)n_nodes * 4);    // N+1
    int*   sorted_src = offs + n_nodes + 1;                 // E
    float* base   = (float*)d_out;

    prep_weights<<<1, BLK, 0, stream>>>(W, skip_W, conv_bias, skip_b,
                                        att_src, att_dst, wfrag, bias64,
                                        watt_s, watt_d, bcur);

    node_bucket<<<nbNode + nbB, BLK, 0, stream>>>(
        x, wfrag, bias64, watt_s, watt_d, h16, base, a_src, a_dst, n_nodes,
        ei_raw, bcur, tmp, n_edges, nbNode);

    scatter2<<<nbBucket, BLK, 0, stream>>>(tmp, bcur, offs, sorted_src,
                                           n_nodes, n_edges, nbBucket);

    aggregate_kernel<<<(n_nodes + 31) / 32, BLK, 0, stream>>>(
        sorted_src, offs, h16, a_src, a_dst, (float*)d_out, n_nodes);
}